// Round 8
// baseline (702.462 us; speedup 1.0000x reference)
//
#include <hip/hip_runtime.h>
#include <hip/hip_cooperative_groups.h>
#include <math.h>

namespace cg = cooperative_groups;

typedef unsigned int  u32;
typedef unsigned short u16;

#define TILE1 8192      // edges per pass-1 block (16/thread @ 512 threads)
#define BKW   256       // nodes per bucket (shift 8)
#define CAP   9216      // tmp slots per bucket (mean 8192, +11 sigma)

typedef __attribute__((ext_vector_type(8))) short bf16x8;
typedef __attribute__((ext_vector_type(4))) float f32x4;
typedef __attribute__((ext_vector_type(2))) float f32x2;
union frag_u { bf16x8 v; u32 u[4]; uint4 q; };

__device__ inline u32 bf16_rne(float f) {
    u32 u = __float_as_uint(f);
    return (u + 0x7FFFu + ((u >> 16) & 1u)) >> 16;
}
__device__ inline float bf_lo(u32 u) { return __uint_as_float(u << 16); }
__device__ inline float bf_hi(u32 u) { return __uint_as_float(u & 0xFFFF0000u); }

__device__ inline f32x2 up2(u32 u) {
    f32x2 t;
    t.x = __uint_as_float(u << 16);
    t.y = __uint_as_float(u & 0xFFFF0000u);
    return t;
}
__device__ inline void add8p(f32x2* a, uint4 q) {
    a[0] += up2(q.x); a[1] += up2(q.y); a[2] += up2(q.z); a[3] += up2(q.w);
}

// relu on packed bf16x2: clear halves whose sign bit is set
__device__ inline u32 relu_pk(u32 v) {
    u32 s = v & 0x80008000u;
    u32 m = (s >> 15) * 0xFFFFu;
    return v & ~m;
}

// ================= CSR build: 2-pass radix partition =================

__global__ __launch_bounds__(512) void k_part1(const int* __restrict__ ei,
                                               int* __restrict__ bucketCur,
                                               u32* __restrict__ tmp,
                                               int E, int N, int NBK) {
    __shared__ int hist[2048];    // 4 replicas for count; [0:512) reused as cursor
    __shared__ int base[512];
    const int tid = threadIdx.x;
    if (tid < NBK) {
        hist[tid] = 0; hist[512 + tid] = 0;
        hist[1024 + tid] = 0; hist[1536 + tid] = 0;
    }
    __syncthreads();

    const int rep = (tid & 3) << 9;
    const int t0 = blockIdx.x * TILE1;
    const int4* ei4s = (const int4*)ei;             // E % 4 == 0
    const int4* ei4d = (const int4*)(ei + E);
    const int q0 = t0 >> 2;
    const int QE = E >> 2;

    int sv[16], dv[16], key[16];
#pragma unroll
    for (int j = 0; j < 4; ++j) {
        int qi = q0 + j * 512 + tid;
        int4 s4 = make_int4(0, 0, 0, 0), d4 = make_int4(-1, -1, -1, -1);
        if (qi < QE) { s4 = ei4s[qi]; d4 = ei4d[qi]; }
        sv[4 * j + 0] = s4.x; dv[4 * j + 0] = d4.x;
        sv[4 * j + 1] = s4.y; dv[4 * j + 1] = d4.y;
        sv[4 * j + 2] = s4.z; dv[4 * j + 2] = d4.z;
        sv[4 * j + 3] = s4.w; dv[4 * j + 3] = d4.w;
    }
#pragma unroll
    for (int j = 0; j < 16; ++j) {
        key[j] = -1;
        if ((unsigned)dv[j] < (unsigned)N && (unsigned)sv[j] < (unsigned)N) {
            key[j] = dv[j] >> 8;
            atomicAdd(&hist[key[j] + rep], 1);
        }
    }
    __syncthreads();
    if (tid < NBK) {
        int tot = hist[tid] + hist[512 + tid] + hist[1024 + tid] + hist[1536 + tid];
        base[tid] = atomicAdd(&bucketCur[tid], tot);
        hist[tid] = 0;                 // running cursor for placement
    }
    __syncthreads();
#pragma unroll
    for (int j = 0; j < 16; ++j) {
        if (key[j] >= 0) {
            int slot = atomicAdd(&hist[key[j]], 1);
            int off = base[key[j]] + slot;
            if (off < CAP)
                tmp[(size_t)key[j] * CAP + off] =
                    ((u32)(dv[j] & 255) << 17) | (u32)sv[j];
        }
    }
}

__global__ __launch_bounds__(512) void k_part2(const int* __restrict__ bucketCnt,
                                               const u32* __restrict__ tmp,
                                               int* __restrict__ csr,
                                               int* __restrict__ rowptr,
                                               float* __restrict__ dis,
                                               int N, int NBK) {
    __shared__ int hist[256];
    __shared__ int ts[512];
    __shared__ int sStart;
    const int b = blockIdx.x;
    const int t = threadIdx.x;

    int myCnt = (t < NBK) ? bucketCnt[t] : 0;
    ts[t] = myCnt;
    __syncthreads();
    for (int off = 1; off < 512; off <<= 1) {
        int u = (t >= off) ? ts[t - off] : 0;
        __syncthreads();
        ts[t] += u;
        __syncthreads();
    }
    if (t == b) sStart = ts[t] - myCnt;
    if (b == 0 && t == NBK - 1) rowptr[N] = ts[t];
    __syncthreads();
    const int start = sStart;
    const int cnt = bucketCnt[b];
    const u32* src = tmp + (size_t)b * CAP;

    if (t < 256) hist[t] = 0;
    __syncthreads();
    for (int i = t; i < cnt; i += 512)
        atomicAdd(&hist[src[i] >> 17], 1);
    __syncthreads();

    int h = (t < 256) ? hist[t] : 0;
    ts[t] = h;
    __syncthreads();
    for (int off = 1; off < 512; off <<= 1) {
        int u = (t >= off) ? ts[t - off] : 0;
        __syncthreads();
        ts[t] += u;
        __syncthreads();
    }
    if (t < 256) hist[t] = ts[t] - h;       // exclusive
    __syncthreads();

    if (t < 256) {
        int gn = (b << 8) + t;
        if (gn < N) {
            int e0 = hist[t];
            int e1 = (t < 255) ? hist[t + 1] : cnt;
            rowptr[gn] = start + e0;
            dis[gn] = rsqrtf((float)(e1 - e0) + 1.0f);
        }
    }
    __syncthreads();

    for (int i = t; i < cnt; i += 512) {
        u32 v = src[i];
        int p = atomicAdd(&hist[v >> 17], 1);
        csr[start + p] = (int)(v & 0x1FFFFu);
    }
}

// ========== weight convert (+ bucketCur zero): n-major bf16 hi/lo tables ==========

__global__ __launch_bounds__(256) void k_convW(
    const float* __restrict__ W1, const float* __restrict__ W2,
    u32* __restrict__ W1h, u32* __restrict__ W1l,
    u32* __restrict__ W2h, u32* __restrict__ W2l,
    int* __restrict__ bucketCur, int NBK)
{
    int idx = blockIdx.x * 256 + threadIdx.x;
    if (idx < NBK) bucketCur[idx] = 0;
    if (idx < 8192) {
        int n = idx >> 6, k = (idx & 63) * 2;
        float w0 = W1[k * 128 + n], w1 = W1[(k + 1) * 128 + n];
        u32 h0 = bf16_rne(w0), h1 = bf16_rne(w1);
        u32 l0 = bf16_rne(w0 - __uint_as_float(h0 << 16));
        u32 l1 = bf16_rne(w1 - __uint_as_float(h1 << 16));
        W1h[idx] = h0 | (h1 << 16);
        W1l[idx] = l0 | (l1 << 16);
    } else if (idx < 12288) {
        int i2 = idx - 8192;
        int n = i2 >> 6, k = (i2 & 63) * 2;
        float w0 = W2[k * 64 + n], w1 = W2[(k + 1) * 64 + n];
        u32 h0 = bf16_rne(w0), h1 = bf16_rne(w1);
        u32 l0 = bf16_rne(w0 - __uint_as_float(h0 << 16));
        u32 l1 = bf16_rne(w1 - __uint_as_float(h1 << 16));
        W2h[i2] = h0 | (h1 << 16);
        W2l[i2] = l0 | (l1 << 16);
    }
}

// ========== GEMM1 (MFMA, LDS-staged W): Hb1 = bf16( (X @ W1) * dis ) ==========
// 2 M-tiles per wave (32 rows). Block covers 128 rows; 64 KB LDS, XOR-swizzled.

__global__ __launch_bounds__(256) void k_gemm1m(
    const float* __restrict__ X, const u32* __restrict__ Wh,
    const u32* __restrict__ Wl, const float* __restrict__ dis,
    u32* __restrict__ Hb, int M)
{
    __shared__ uint4 sW[4096];
    const int tid = threadIdx.x;
    const uint4* Wh4 = (const uint4*)Wh;
    const uint4* Wl4 = (const uint4*)Wl;
#pragma unroll
    for (int i = 0; i < 8; ++i) {
        int idx = tid + i * 256;          // 0..2047
        int l = idx >> 4, j = idx & 15;
        int js = j ^ (l & 7);
        sW[l * 16 + js] = Wh4[idx];
        sW[2048 + l * 16 + js] = Wl4[idx];
    }
    __syncthreads();

    const int w = tid >> 6, lane = tid & 63;
    const int mrow = blockIdx.x * 128 + w * 32;
    const int m16 = lane & 15, quad = lane >> 4;

    frag_u Ah[2][4], Al[2][4];
#pragma unroll
    for (int t = 0; t < 2; ++t) {
        int gm = mrow + t * 16 + m16; if (gm >= M) gm = M - 1;
        const float* xr = X + (size_t)gm * 128;
#pragma unroll
        for (int kt = 0; kt < 4; ++kt) {
            int kb = kt * 32 + quad * 8;
            float4 xa = *(const float4*)(xr + kb);
            float4 xb = *(const float4*)(xr + kb + 4);
            float xe[8] = {xa.x, xa.y, xa.z, xa.w, xb.x, xb.y, xb.z, xb.w};
#pragma unroll
            for (int j = 0; j < 4; ++j) {
                u32 h0 = bf16_rne(xe[2 * j]),     h1 = bf16_rne(xe[2 * j + 1]);
                u32 l0 = bf16_rne(xe[2 * j]     - __uint_as_float(h0 << 16));
                u32 l1 = bf16_rne(xe[2 * j + 1] - __uint_as_float(h1 << 16));
                Ah[t][kt].u[j] = h0 | (h1 << 16);
                Al[t][kt].u[j] = l0 | (l1 << 16);
            }
        }
    }

    float dv[2][4];
#pragma unroll
    for (int t = 0; t < 2; ++t)
#pragma unroll
        for (int r = 0; r < 4; ++r) {
            int gR = mrow + t * 16 + quad * 4 + r;
            dv[t][r] = (gR < M) ? dis[gR] : 0.f;
        }

#pragma unroll
    for (int nt = 0; nt < 8; ++nt) {
        f32x4 acc0 = {0.f, 0.f, 0.f, 0.f};
        f32x4 acc1 = {0.f, 0.f, 0.f, 0.f};
        int l = nt * 16 + m16;
        int swz = l & 7;
#pragma unroll
        for (int kt = 0; kt < 4; ++kt) {
            frag_u Bh, Bl;
            int jb = (kt * 4 + quad) ^ swz;
            Bh.q = sW[l * 16 + jb];
            Bl.q = sW[2048 + l * 16 + jb];
            acc0 = __builtin_amdgcn_mfma_f32_16x16x32_bf16(Al[0][kt].v, Bh.v, acc0, 0, 0, 0);
            acc0 = __builtin_amdgcn_mfma_f32_16x16x32_bf16(Ah[0][kt].v, Bl.v, acc0, 0, 0, 0);
            acc0 = __builtin_amdgcn_mfma_f32_16x16x32_bf16(Ah[0][kt].v, Bh.v, acc0, 0, 0, 0);
            acc1 = __builtin_amdgcn_mfma_f32_16x16x32_bf16(Al[1][kt].v, Bh.v, acc1, 0, 0, 0);
            acc1 = __builtin_amdgcn_mfma_f32_16x16x32_bf16(Ah[1][kt].v, Bl.v, acc1, 0, 0, 0);
            acc1 = __builtin_amdgcn_mfma_f32_16x16x32_bf16(Ah[1][kt].v, Bh.v, acc1, 0, 0, 0);
        }
#pragma unroll
        for (int r = 0; r < 4; ++r) {
            float vs0 = acc0[r] * dv[0][r];
            float vo0 = __shfl_xor(vs0, 1, 64);
            float vs1 = acc1[r] * dv[1][r];
            float vo1 = __shfl_xor(vs1, 1, 64);
            if ((m16 & 1) == 0) {
                int gR0 = mrow + quad * 4 + r;
                if (gR0 < M)
                    Hb[(size_t)gR0 * 64 + nt * 8 + (m16 >> 1)] =
                        bf16_rne(vs0) | (bf16_rne(vo0) << 16);
                int gR1 = mrow + 16 + quad * 4 + r;
                if (gR1 < M)
                    Hb[(size_t)gR1 * 64 + nt * 8 + (m16 >> 1)] =
                        bf16_rne(vs1) | (bf16_rne(vo1) << 16);
            }
        }
    }
}

// ========= pool helper =========

__device__ inline int lower_bound(const int* __restrict__ b, int n, int v) {
    int lo = 0, hi = n;
    while (lo < hi) { int m = (lo + hi) >> 1; if (b[m] < v) lo = m + 1; else hi = m; }
    return lo;
}

// ============================================================================
// Cooperative fused back-half v3: agg1(both halves) -> gemm2 -> agg2 -> pool+fc.
// v2 (R7) fixed the spill but LDS=34KB capped occupancy at 23% -> gather
// phases ran at half throughput. v3: static LDS = 1.3KB (pool scratch only);
// phase B reads W2 hi/lo straight from global (32KB, L2-broadcast, phase B is
// ~20us of work). Occupancy -> VGPR-limited (~5 waves/SIMD, ~62%).
// NO atomics; phases separated by __threadfence + grid.sync (proven correct).
// ============================================================================

__global__ __launch_bounds__(256) void k_coop(
    const int* rowptr, const int* csr, const float* dis,
    const u32* Hb1, const float* b1, u32* agg1b,
    const u32* W2h, const u32* W2l,
    u32* Hb2, const float* b2, u32* agg2b,
    const int* batch, const float* Wfc, const float* bfc,
    float* out, int N, int ng)
{
    __shared__ float sPool[320];       // pool: red[256] + mean[64]
    cg::grid_group gg = cg::this_grid();
    const int tid = threadIdx.x;
    const int gsz = gridDim.x * 256;

    // ---- phase A: aggregate layer 1 (both column halves) ----
    {
        const char* hb = (const char*)Hb1;
        const int li = tid & 7;
        const int total = N * 16;          // (node, half) x 8 lanes
        for (int idx = blockIdx.x * 256 + tid; idx < total; idx += gsz) {
            int n = idx >> 4;
            u32 off = (u32)((((idx >> 3) & 1) << 7) + (li << 4));
            int e = rowptr[n];
            int s1 = rowptr[n + 1];
            float dn = dis[n];
            f32x2 acc[4];
#pragma unroll
            for (int j = 0; j < 4; ++j) acc[j] = 0.f;

            for (; e + 8 <= s1; e += 8) {
                u32 a0 = (u32)csr[e + 0] << 8; u32 a1 = (u32)csr[e + 1] << 8;
                u32 a2 = (u32)csr[e + 2] << 8; u32 a3 = (u32)csr[e + 3] << 8;
                u32 a4 = (u32)csr[e + 4] << 8; u32 a5 = (u32)csr[e + 5] << 8;
                u32 a6 = (u32)csr[e + 6] << 8; u32 a7 = (u32)csr[e + 7] << 8;
                uint4 q0 = *(const uint4*)(hb + a0 + off);
                uint4 q1 = *(const uint4*)(hb + a1 + off);
                uint4 q2 = *(const uint4*)(hb + a2 + off);
                uint4 q3 = *(const uint4*)(hb + a3 + off);
                uint4 q4 = *(const uint4*)(hb + a4 + off);
                uint4 q5 = *(const uint4*)(hb + a5 + off);
                uint4 q6 = *(const uint4*)(hb + a6 + off);
                uint4 q7 = *(const uint4*)(hb + a7 + off);
                add8p(acc, q0); add8p(acc, q1); add8p(acc, q2); add8p(acc, q3);
                add8p(acc, q4); add8p(acc, q5); add8p(acc, q6); add8p(acc, q7);
            }
            for (; e + 2 <= s1; e += 2) {
                u32 a0 = (u32)csr[e + 0] << 8; u32 a1 = (u32)csr[e + 1] << 8;
                uint4 q0 = *(const uint4*)(hb + a0 + off);
                uint4 q1 = *(const uint4*)(hb + a1 + off);
                add8p(acc, q0); add8p(acc, q1);
            }
            if (e < s1) {
                u32 a0 = (u32)csr[e] << 8;
                uint4 q0 = *(const uint4*)(hb + a0 + off);
                add8p(acc, q0);
            }
            {   // self-loop
                uint4 q = *(const uint4*)(hb + ((u32)n << 8) + off);
                add8p(acc, q);
            }

            float4 bb0 = ((const float4*)b1)[off >> 3];
            float4 bb1 = ((const float4*)b1)[(off >> 3) + 1];
            uint4 p;
            p.x = bf16_rne(fmaf(dn, acc[0].x, bb0.x)) | (bf16_rne(fmaf(dn, acc[0].y, bb0.y)) << 16);
            p.y = bf16_rne(fmaf(dn, acc[1].x, bb0.z)) | (bf16_rne(fmaf(dn, acc[1].y, bb0.w)) << 16);
            p.z = bf16_rne(fmaf(dn, acc[2].x, bb1.x)) | (bf16_rne(fmaf(dn, acc[2].y, bb1.y)) << 16);
            p.w = bf16_rne(fmaf(dn, acc[3].x, bb1.z)) | (bf16_rne(fmaf(dn, acc[3].y, bb1.w)) << 16);
            ((uint4*)agg1b)[(size_t)n * 16 + (off >> 4)] = p;
        }
    }
    __threadfence();
    gg.sync();

    // ---- phase B: gemm2 = bf16( (relu(agg1b) @ W2) * dis ), 1 M-tile/wave,
    //      B-fragments read from global (L2-broadcast) ----
    {
        const int w = tid >> 6, lane = tid & 63;
        const int m16 = lane & 15, quad = lane >> 4;
        const uint4* X4 = (const uint4*)agg1b;
        const uint4* Wh4 = (const uint4*)W2h;
        const uint4* Wl4 = (const uint4*)W2l;
        const int ntile = (N + 63) >> 6;
        for (int mt = blockIdx.x; mt < ntile; mt += gridDim.x) {
            const int mrow = mt * 64 + w * 16;
            int gm = mrow + m16; if (gm >= N) gm = N - 1;

            frag_u A[4];
#pragma unroll
            for (int kt = 0; kt < 4; ++kt) {
                A[kt].q = X4[(size_t)gm * 16 + kt * 4 + quad];
#pragma unroll
                for (int j = 0; j < 4; ++j) A[kt].u[j] = relu_pk(A[kt].u[j]);
            }

            float dv[4];
#pragma unroll
            for (int r = 0; r < 4; ++r) {
                int gR = mrow + quad * 4 + r;
                dv[r] = (gR < N) ? dis[gR] : 0.f;
            }

#pragma unroll
            for (int nt = 0; nt < 4; ++nt) {
                f32x4 acc = {0.f, 0.f, 0.f, 0.f};
                int l = nt * 16 + m16;
#pragma unroll
                for (int kt = 0; kt < 4; ++kt) {
                    frag_u Bh, Bl;
                    Bh.q = Wh4[l * 16 + kt * 4 + quad];
                    Bl.q = Wl4[l * 16 + kt * 4 + quad];
                    acc = __builtin_amdgcn_mfma_f32_16x16x32_bf16(A[kt].v, Bl.v, acc, 0, 0, 0);
                    acc = __builtin_amdgcn_mfma_f32_16x16x32_bf16(A[kt].v, Bh.v, acc, 0, 0, 0);
                }
#pragma unroll
                for (int r = 0; r < 4; ++r) {
                    float vs = acc[r] * dv[r];
                    float vo = __shfl_xor(vs, 1, 64);
                    if ((m16 & 1) == 0) {
                        int gR = mrow + quad * 4 + r;
                        if (gR < N)
                            Hb2[(size_t)gR * 32 + nt * 8 + (m16 >> 1)] =
                                bf16_rne(vs) | (bf16_rne(vo) << 16);
                    }
                }
            }
        }
    }
    __threadfence();
    gg.sync();

    // ---- phase C: aggregate layer 2 ----
    {
        const char* hb = (const char*)Hb2;
        const int li = tid & 7;
        const u32 off = (u32)(li << 4);
        const int total = N * 8;
        for (int idx = blockIdx.x * 256 + tid; idx < total; idx += gsz) {
            int n = idx >> 3;
            int e = rowptr[n];
            int s1 = rowptr[n + 1];
            float dn = dis[n];
            f32x2 acc[4];
#pragma unroll
            for (int j = 0; j < 4; ++j) acc[j] = 0.f;

            for (; e + 8 <= s1; e += 8) {
                u32 a0 = (u32)csr[e + 0] << 7; u32 a1 = (u32)csr[e + 1] << 7;
                u32 a2 = (u32)csr[e + 2] << 7; u32 a3 = (u32)csr[e + 3] << 7;
                u32 a4 = (u32)csr[e + 4] << 7; u32 a5 = (u32)csr[e + 5] << 7;
                u32 a6 = (u32)csr[e + 6] << 7; u32 a7 = (u32)csr[e + 7] << 7;
                uint4 q0 = *(const uint4*)(hb + a0 + off);
                uint4 q1 = *(const uint4*)(hb + a1 + off);
                uint4 q2 = *(const uint4*)(hb + a2 + off);
                uint4 q3 = *(const uint4*)(hb + a3 + off);
                uint4 q4 = *(const uint4*)(hb + a4 + off);
                uint4 q5 = *(const uint4*)(hb + a5 + off);
                uint4 q6 = *(const uint4*)(hb + a6 + off);
                uint4 q7 = *(const uint4*)(hb + a7 + off);
                add8p(acc, q0); add8p(acc, q1); add8p(acc, q2); add8p(acc, q3);
                add8p(acc, q4); add8p(acc, q5); add8p(acc, q6); add8p(acc, q7);
            }
            for (; e + 2 <= s1; e += 2) {
                u32 a0 = (u32)csr[e + 0] << 7; u32 a1 = (u32)csr[e + 1] << 7;
                uint4 q0 = *(const uint4*)(hb + a0 + off);
                uint4 q1 = *(const uint4*)(hb + a1 + off);
                add8p(acc, q0); add8p(acc, q1);
            }
            if (e < s1) {
                u32 a0 = (u32)csr[e] << 7;
                uint4 q0 = *(const uint4*)(hb + a0 + off);
                add8p(acc, q0);
            }
            {
                uint4 q = *(const uint4*)(hb + ((u32)n << 7) + off);
                add8p(acc, q);
            }

            float4 bb0 = ((const float4*)b2)[off >> 3];
            float4 bb1 = ((const float4*)b2)[(off >> 3) + 1];
            uint4 p;
            p.x = bf16_rne(fmaf(dn, acc[0].x, bb0.x)) | (bf16_rne(fmaf(dn, acc[0].y, bb0.y)) << 16);
            p.y = bf16_rne(fmaf(dn, acc[1].x, bb0.z)) | (bf16_rne(fmaf(dn, acc[1].y, bb0.w)) << 16);
            p.z = bf16_rne(fmaf(dn, acc[2].x, bb1.x)) | (bf16_rne(fmaf(dn, acc[2].y, bb1.y)) << 16);
            p.w = bf16_rne(fmaf(dn, acc[3].x, bb1.z)) | (bf16_rne(fmaf(dn, acc[3].y, bb1.w)) << 16);
            ((uint4*)agg2b)[(size_t)n * 8 + (off >> 4)] = p;
        }
    }
    __threadfence();
    gg.sync();

    // ---- phase D: mean-pool + classifier (one graph per block) ----
    {
        float* red  = sPool;           // 256 floats
        float* mean = sPool + 256;     // 64 floats
        const int f = tid & 63, stripe = tid >> 6;
        const int ui = f >> 1, hi = f & 1;
        for (int g = blockIdx.x; g < ng; g += gridDim.x) {
            int start = lower_bound(batch, N, g);
            int end   = lower_bound(batch, N, g + 1);
            float acc = 0.f;
            for (int i = start + stripe; i < end; i += 4) {
                u32 v = agg2b[(size_t)i * 32 + ui];
                acc += hi ? bf_hi(v) : bf_lo(v);
            }
            red[tid] = acc;
            __syncthreads();
            if (tid < 64) {
                float s = red[tid] + red[tid + 64] + red[tid + 128] + red[tid + 192];
                float c = (float)(end - start);
                mean[tid] = s / fmaxf(c, 1.0f);
            }
            __syncthreads();
            if (tid < 10) {
                float o = bfc[tid];
                for (int k = 0; k < 64; ++k)
                    o = fmaf(mean[k], Wfc[k * 10 + tid], o);
                out[g * 10 + tid] = o;
            }
            __syncthreads();
        }
    }
}

// ======== fallback separate kernels (used only if coop launch refused) ========

template <int SH, int POFF>
__global__ __launch_bounds__(256) void k_aggh(
    const int* __restrict__ rowptr, const int* __restrict__ csr,
    const float* __restrict__ dis, const u32* __restrict__ Hb,
    const float* __restrict__ bias, u32* __restrict__ AGGb, int N)
{
    int gid = blockIdx.x * 256 + threadIdx.x;
    int n = gid >> 3;
    int li = threadIdx.x & 7;
    if (n >= N) return;
    int e = rowptr[n];
    int s1 = rowptr[n + 1];
    const float dn = dis[n];
    const char* hb = (const char*)Hb;
    const u32 off = (u32)(POFF + li * 16);

    f32x2 acc[4];
#pragma unroll
    for (int j = 0; j < 4; ++j) acc[j] = 0.f;

    for (; e + 8 <= s1; e += 8) {
        u32 a0 = (u32)csr[e + 0] << SH; u32 a1 = (u32)csr[e + 1] << SH;
        u32 a2 = (u32)csr[e + 2] << SH; u32 a3 = (u32)csr[e + 3] << SH;
        u32 a4 = (u32)csr[e + 4] << SH; u32 a5 = (u32)csr[e + 5] << SH;
        u32 a6 = (u32)csr[e + 6] << SH; u32 a7 = (u32)csr[e + 7] << SH;
        uint4 q0 = *(const uint4*)(hb + a0 + off);
        uint4 q1 = *(const uint4*)(hb + a1 + off);
        uint4 q2 = *(const uint4*)(hb + a2 + off);
        uint4 q3 = *(const uint4*)(hb + a3 + off);
        uint4 q4 = *(const uint4*)(hb + a4 + off);
        uint4 q5 = *(const uint4*)(hb + a5 + off);
        uint4 q6 = *(const uint4*)(hb + a6 + off);
        uint4 q7 = *(const uint4*)(hb + a7 + off);
        add8p(acc, q0); add8p(acc, q1); add8p(acc, q2); add8p(acc, q3);
        add8p(acc, q4); add8p(acc, q5); add8p(acc, q6); add8p(acc, q7);
    }
    for (; e + 2 <= s1; e += 2) {
        u32 a0 = (u32)csr[e + 0] << SH; u32 a1 = (u32)csr[e + 1] << SH;
        uint4 q0 = *(const uint4*)(hb + a0 + off);
        uint4 q1 = *(const uint4*)(hb + a1 + off);
        add8p(acc, q0); add8p(acc, q1);
    }
    if (e < s1) {
        u32 a0 = (u32)csr[e] << SH;
        uint4 q0 = *(const uint4*)(hb + a0 + off);
        add8p(acc, q0);
    }
    {
        uint4 q = *(const uint4*)(hb + ((u32)n << SH) + off);
        add8p(acc, q);
    }

    float4 bb0 = ((const float4*)bias)[POFF / 8 + li * 2 + 0];
    float4 bb1 = ((const float4*)bias)[POFF / 8 + li * 2 + 1];
    uint4 p;
    p.x = bf16_rne(fmaf(dn, acc[0].x, bb0.x)) | (bf16_rne(fmaf(dn, acc[0].y, bb0.y)) << 16);
    p.y = bf16_rne(fmaf(dn, acc[1].x, bb0.z)) | (bf16_rne(fmaf(dn, acc[1].y, bb0.w)) << 16);
    p.z = bf16_rne(fmaf(dn, acc[2].x, bb1.x)) | (bf16_rne(fmaf(dn, acc[2].y, bb1.y)) << 16);
    p.w = bf16_rne(fmaf(dn, acc[3].x, bb1.z)) | (bf16_rne(fmaf(dn, acc[3].y, bb1.w)) << 16);
    ((uint4*)AGGb)[(size_t)n * (1 << (SH - 4)) + POFF / 16 + li] = p;
}

__global__ __launch_bounds__(256) void k_gemm2m(
    const u32* __restrict__ Xb, const u32* __restrict__ Wh,
    const u32* __restrict__ Wl, const float* __restrict__ dis,
    u32* __restrict__ Hb, int M)
{
    __shared__ uint4 sW[2176];
    const int tid = threadIdx.x;
    const uint4* Wh4 = (const uint4*)Wh;
    const uint4* Wl4 = (const uint4*)Wl;
#pragma unroll
    for (int i = 0; i < 4; ++i) {
        int idx = tid + i * 256;
        int l = idx >> 4, j = idx & 15;
        sW[l * 17 + j] = Wh4[l * 16 + j];
        sW[1088 + l * 17 + j] = Wl4[l * 16 + j];
    }
    __syncthreads();

    const int w = tid >> 6, lane = tid & 63;
    const int mrow = blockIdx.x * 128 + w * 32;
    const int m16 = lane & 15, quad = lane >> 4;

    const uint4* X4 = (const uint4*)Xb;
    frag_u A[2][4];
#pragma unroll
    for (int t = 0; t < 2; ++t) {
        int gm = mrow + t * 16 + m16; if (gm >= M) gm = M - 1;
#pragma unroll
        for (int kt = 0; kt < 4; ++kt) {
            A[t][kt].q = X4[(size_t)gm * 16 + kt * 4 + quad];
#pragma unroll
            for (int j = 0; j < 4; ++j) A[t][kt].u[j] = relu_pk(A[t][kt].u[j]);
        }
    }

    float dv[2][4];
#pragma unroll
    for (int t = 0; t < 2; ++t)
#pragma unroll
        for (int r = 0; r < 4; ++r) {
            int gR = mrow + t * 16 + quad * 4 + r;
            dv[t][r] = (gR < M) ? dis[gR] : 0.f;
        }

#pragma unroll
    for (int nt = 0; nt < 4; ++nt) {
        f32x4 acc0 = {0.f, 0.f, 0.f, 0.f};
        f32x4 acc1 = {0.f, 0.f, 0.f, 0.f};
        int l = nt * 16 + m16;
#pragma unroll
        for (int kt = 0; kt < 4; ++kt) {
            frag_u Bh, Bl;
            Bh.q = sW[l * 17 + kt * 4 + quad];
            Bl.q = sW[1088 + l * 17 + kt * 4 + quad];
            acc0 = __builtin_amdgcn_mfma_f32_16x16x32_bf16(A[0][kt].v, Bl.v, acc0, 0, 0, 0);
            acc0 = __builtin_amdgcn_mfma_f32_16x16x32_bf16(A[0][kt].v, Bh.v, acc0, 0, 0, 0);
            acc1 = __builtin_amdgcn_mfma_f32_16x16x32_bf16(A[1][kt].v, Bl.v, acc1, 0, 0, 0);
            acc1 = __builtin_amdgcn_mfma_f32_16x16x32_bf16(A[1][kt].v, Bh.v, acc1, 0, 0, 0);
        }
#pragma unroll
        for (int r = 0; r < 4; ++r) {
            float vs0 = acc0[r] * dv[0][r];
            float vo0 = __shfl_xor(vs0, 1, 64);
            float vs1 = acc1[r] * dv[1][r];
            float vo1 = __shfl_xor(vs1, 1, 64);
            if ((m16 & 1) == 0) {
                int gR0 = mrow + quad * 4 + r;
                if (gR0 < M)
                    Hb[(size_t)gR0 * 32 + nt * 8 + (m16 >> 1)] =
                        bf16_rne(vs0) | (bf16_rne(vo0) << 16);
                int gR1 = mrow + 16 + quad * 4 + r;
                if (gR1 < M)
                    Hb[(size_t)gR1 * 32 + nt * 8 + (m16 >> 1)] =
                        bf16_rne(vs1) | (bf16_rne(vo1) << 16);
            }
        }
    }
}

__global__ __launch_bounds__(256) void k_poolfc(
    const int* __restrict__ batch, const u32* __restrict__ AGGb2,
    const float* __restrict__ Wfc, const float* __restrict__ bfc,
    float* __restrict__ out, int n)
{
    int g = blockIdx.x;
    int start = lower_bound(batch, n, g);
    int end   = lower_bound(batch, n, g + 1);
    int tid = threadIdx.x;
    int f = tid & 63, stripe = tid >> 6;
    int ui = f >> 1, hi = f & 1;
    float acc = 0.f;
    for (int i = start + stripe; i < end; i += 4) {
        u32 v = AGGb2[(size_t)i * 32 + ui];
        acc += hi ? bf_hi(v) : bf_lo(v);
    }
    __shared__ float red[256];
    __shared__ float mean[64];
    red[tid] = acc;
    __syncthreads();
    if (tid < 64) {
        float s = red[tid] + red[tid + 64] + red[tid + 128] + red[tid + 192];
        float c = (float)(end - start);
        mean[tid] = s / fmaxf(c, 1.0f);
    }
    __syncthreads();
    if (tid < 10) {
        float o = bfc[tid];
        for (int k = 0; k < 64; ++k)
            o = fmaf(mean[k], Wfc[k * 10 + tid], o);
        out[g * 10 + tid] = o;
    }
}

// ================= launch =================

extern "C" void kernel_launch(void* const* d_in, const int* in_sizes, int n_in,
                              void* d_out, int out_size, void* d_ws, size_t ws_size,
                              hipStream_t stream)
{
    const float* x    = (const float*)d_in[0];
    const int*   ei   = (const int*)d_in[1];
    const int*   batch= (const int*)d_in[2];
    const float* W1   = (const float*)d_in[3];
    const float* b1   = (const float*)d_in[4];
    const float* W2   = (const float*)d_in[5];
    const float* b2   = (const float*)d_in[6];
    const float* Wfc  = (const float*)d_in[7];
    const float* bfc  = (const float*)d_in[8];
    float* out = (float*)d_out;

    const int N  = in_sizes[0] / 128;     // 100000
    const int E  = in_sizes[1] / 2;       // 3200000
    const int ng = out_size / 10;         // 256

    const int NBK = (N + BKW - 1) / BKW;  // 391 buckets

    // ---- workspace layout (words) ----
    int*   rowptr    = (int*)d_ws;                          // 102400 (N+1)
    int*   bucketCur = rowptr + 102400;                     // 512
    float* dis       = (float*)(bucketCur + 512);           // 102400
    int*   csr       = (int*)(dis + 102400);                // E
    u32*   tmp       = (u32*)(csr + E);
    u32*   Hb1       = tmp;                                     // N*64 u32 (aliases tmp)
    u32*   agg1b     = (u32*)((int*)tmp + (size_t)N * 64);      // N*64 u32 (bf16 packed)
    u16*   Hb2       = (u16*)((int*)agg1b + (size_t)N * 128);   // N*64 u16
    u32*   W1h       = (u32*)((int*)Hb2 + (size_t)N * 32);      // 8192
    u32*   W1l       = W1h + 8192;                              // 8192
    u32*   W2h       = W1l + 8192;                              // 4096
    u32*   W2l       = W2h + 4096;                              // 4096
    u32*   agg2b     = W2l + 4096;                              // N*32 u32 (fresh region:
                                                                // cross-XCD stale-line safety)

    // ---- front half: weight convert + CSR build + gemm1 (4 kernels) ----
    k_convW<<<48, 256, 0, stream>>>(W1, W2, W1h, W1l, W2h, W2l, bucketCur, NBK);
    k_part1<<<(E + TILE1 - 1) / TILE1, 512, 0, stream>>>(ei, bucketCur, tmp, E, N, NBK);
    k_part2<<<NBK, 512, 0, stream>>>(bucketCur, tmp, csr, rowptr, dis, N, NBK);
    k_gemm1m<<<(N + 127) / 128, 256, 0, stream>>>(x, W1h, W1l, dis, Hb1, N);

    // ---- back half: one cooperative kernel (agg1 + gemm2 + agg2 + pool) ----
    static int coopBlocks = -1;
    if (coopBlocks < 0) {
        int nb = 0, ncu = 0, dev = 0;
        hipGetDevice(&dev);
        hipDeviceGetAttribute(&ncu, hipDeviceAttributeMultiprocessorCount, dev);
        hipOccupancyMaxActiveBlocksPerMultiprocessor(&nb, (const void*)k_coop, 256, 0);
        if (nb < 1) nb = 1;
        if (ncu < 1) ncu = 256;
        coopBlocks = nb * ncu;
        if (coopBlocks > 2048) coopBlocks = 2048;
    }

    const u32* Hb2c = (const u32*)Hb2;
    void* hb2p = (void*)Hb2;
    void* args[] = {
        (void*)&rowptr, (void*)&csr, (void*)&dis,
        (void*)&Hb1, (void*)&b1, (void*)&agg1b,
        (void*)&W2h, (void*)&W2l,
        (void*)&hb2p, (void*)&b2, (void*)&agg2b,
        (void*)&batch, (void*)&Wfc, (void*)&bfc,
        (void*)&out, (void*)&N, (void*)&ng
    };

    hipError_t cerr = hipLaunchCooperativeKernel(
        (const void*)k_coop, dim3(coopBlocks), dim3(256), args, 0, stream);

    if (cerr != hipSuccess) {
        // fallback: R3 separate-kernel structure (known-good 384 us)
        k_aggh<8, 0><<<(N * 8 + 255) / 256, 256, 0, stream>>>(rowptr, csr, dis, Hb1, b1, agg1b, N);
        k_aggh<8, 128><<<(N * 8 + 255) / 256, 256, 0, stream>>>(rowptr, csr, dis, Hb1, b1, agg1b, N);
        k_gemm2m<<<(N + 127) / 128, 256, 0, stream>>>(agg1b, W2h, W2l, dis, (u32*)Hb2, N);
        k_aggh<7, 0><<<(N * 8 + 255) / 256, 256, 0, stream>>>(rowptr, csr, dis, Hb2c, b2, agg2b, N);
        k_poolfc<<<ng, 256, 0, stream>>>(batch, agg2b, Wfc, bfc, out, N);
    }
}

// Round 9
// 403.780 us; speedup vs baseline: 1.7397x; 1.7397x over previous
//
#include <hip/hip_runtime.h>
#include <math.h>

typedef unsigned int  u32;
typedef unsigned short u16;

#define TILE1 8192      // edges per pass-1 block (16/thread @ 512 threads)
#define BKW   256       // nodes per bucket (shift 8)
#define CAP   9216      // tmp slots per bucket (mean 8192, +11 sigma)

typedef __attribute__((ext_vector_type(8))) short bf16x8;
typedef __attribute__((ext_vector_type(4))) float f32x4;
typedef __attribute__((ext_vector_type(2))) float f32x2;
union frag_u { bf16x8 v; u32 u[4]; uint4 q; };

__device__ inline u32 bf16_rne(float f) {
    u32 u = __float_as_uint(f);
    return (u + 0x7FFFu + ((u >> 16) & 1u)) >> 16;
}
__device__ inline float bf_lo(u32 u) { return __uint_as_float(u << 16); }
__device__ inline float bf_hi(u32 u) { return __uint_as_float(u & 0xFFFF0000u); }

__device__ inline f32x2 up2(u32 u) {
    f32x2 t;
    t.x = __uint_as_float(u << 16);
    t.y = __uint_as_float(u & 0xFFFF0000u);
    return t;
}
__device__ inline void add8p(f32x2* a, uint4 q) {
    a[0] += up2(q.x); a[1] += up2(q.y); a[2] += up2(q.z); a[3] += up2(q.w);
}

// relu on packed bf16x2: clear halves whose sign bit is set
__device__ inline u32 relu_pk(u32 v) {
    u32 s = v & 0x80008000u;
    u32 m = (s >> 15) * 0xFFFFu;
    return v & ~m;
}

// ================= CSR build: 2-pass radix partition =================

__global__ __launch_bounds__(512) void k_part1(const int* __restrict__ ei,
                                               int* __restrict__ bucketCur,
                                               u32* __restrict__ tmp,
                                               int E, int N, int NBK) {
    __shared__ int hist[2048];    // 4 replicas for count; [0:512) reused as cursor
    __shared__ int base[512];
    const int tid = threadIdx.x;
    if (tid < NBK) {
        hist[tid] = 0; hist[512 + tid] = 0;
        hist[1024 + tid] = 0; hist[1536 + tid] = 0;
    }
    __syncthreads();

    const int rep = (tid & 3) << 9;
    const int t0 = blockIdx.x * TILE1;
    const int4* ei4s = (const int4*)ei;             // E % 4 == 0
    const int4* ei4d = (const int4*)(ei + E);
    const int q0 = t0 >> 2;
    const int QE = E >> 2;

    int sv[16], dv[16], key[16];
#pragma unroll
    for (int j = 0; j < 4; ++j) {
        int qi = q0 + j * 512 + tid;
        int4 s4 = make_int4(0, 0, 0, 0), d4 = make_int4(-1, -1, -1, -1);
        if (qi < QE) { s4 = ei4s[qi]; d4 = ei4d[qi]; }
        sv[4 * j + 0] = s4.x; dv[4 * j + 0] = d4.x;
        sv[4 * j + 1] = s4.y; dv[4 * j + 1] = d4.y;
        sv[4 * j + 2] = s4.z; dv[4 * j + 2] = d4.z;
        sv[4 * j + 3] = s4.w; dv[4 * j + 3] = d4.w;
    }
#pragma unroll
    for (int j = 0; j < 16; ++j) {
        key[j] = -1;
        if ((unsigned)dv[j] < (unsigned)N && (unsigned)sv[j] < (unsigned)N) {
            key[j] = dv[j] >> 8;
            atomicAdd(&hist[key[j] + rep], 1);
        }
    }
    __syncthreads();
    if (tid < NBK) {
        int tot = hist[tid] + hist[512 + tid] + hist[1024 + tid] + hist[1536 + tid];
        base[tid] = atomicAdd(&bucketCur[tid], tot);
        hist[tid] = 0;                 // running cursor for placement
    }
    __syncthreads();
#pragma unroll
    for (int j = 0; j < 16; ++j) {
        if (key[j] >= 0) {
            int slot = atomicAdd(&hist[key[j]], 1);
            int off = base[key[j]] + slot;
            if (off < CAP)
                tmp[(size_t)key[j] * CAP + off] =
                    ((u32)(dv[j] & 255) << 17) | (u32)sv[j];
        }
    }
}

__global__ __launch_bounds__(512) void k_part2(const int* __restrict__ bucketCnt,
                                               const u32* __restrict__ tmp,
                                               int* __restrict__ csr,
                                               int* __restrict__ rowptr,
                                               float* __restrict__ dis,
                                               int N, int NBK) {
    __shared__ int hist[256];
    __shared__ int ts[512];
    __shared__ int sStart;
    const int b = blockIdx.x;
    const int t = threadIdx.x;

    int myCnt = (t < NBK) ? bucketCnt[t] : 0;
    ts[t] = myCnt;
    __syncthreads();
    for (int off = 1; off < 512; off <<= 1) {
        int u = (t >= off) ? ts[t - off] : 0;
        __syncthreads();
        ts[t] += u;
        __syncthreads();
    }
    if (t == b) sStart = ts[t] - myCnt;
    if (b == 0 && t == NBK - 1) rowptr[N] = ts[t];
    __syncthreads();
    const int start = sStart;
    const int cnt = bucketCnt[b];
    const u32* src = tmp + (size_t)b * CAP;

    if (t < 256) hist[t] = 0;
    __syncthreads();
    for (int i = t; i < cnt; i += 512)
        atomicAdd(&hist[src[i] >> 17], 1);
    __syncthreads();

    int h = (t < 256) ? hist[t] : 0;
    ts[t] = h;
    __syncthreads();
    for (int off = 1; off < 512; off <<= 1) {
        int u = (t >= off) ? ts[t - off] : 0;
        __syncthreads();
        ts[t] += u;
        __syncthreads();
    }
    if (t < 256) hist[t] = ts[t] - h;       // exclusive
    __syncthreads();

    if (t < 256) {
        int gn = (b << 8) + t;
        if (gn < N) {
            int e0 = hist[t];
            int e1 = (t < 255) ? hist[t + 1] : cnt;
            rowptr[gn] = start + e0;
            dis[gn] = rsqrtf((float)(e1 - e0) + 1.0f);
        }
    }
    __syncthreads();

    for (int i = t; i < cnt; i += 512) {
        u32 v = src[i];
        int p = atomicAdd(&hist[v >> 17], 1);
        csr[start + p] = (int)(v & 0x1FFFFu);
    }
}

// ========== weight convert (+ bucketCur zero): n-major bf16 hi/lo tables ==========

__global__ __launch_bounds__(256) void k_convW(
    const float* __restrict__ W1, const float* __restrict__ W2,
    u32* __restrict__ W1h, u32* __restrict__ W1l,
    u32* __restrict__ W2h, u32* __restrict__ W2l,
    int* __restrict__ bucketCur, int NBK)
{
    int idx = blockIdx.x * 256 + threadIdx.x;
    if (idx < NBK) bucketCur[idx] = 0;
    if (idx < 8192) {
        int n = idx >> 6, k = (idx & 63) * 2;
        float w0 = W1[k * 128 + n], w1 = W1[(k + 1) * 128 + n];
        u32 h0 = bf16_rne(w0), h1 = bf16_rne(w1);
        u32 l0 = bf16_rne(w0 - __uint_as_float(h0 << 16));
        u32 l1 = bf16_rne(w1 - __uint_as_float(h1 << 16));
        W1h[idx] = h0 | (h1 << 16);
        W1l[idx] = l0 | (l1 << 16);
    } else if (idx < 12288) {
        int i2 = idx - 8192;
        int n = i2 >> 6, k = (i2 & 63) * 2;
        float w0 = W2[k * 64 + n], w1 = W2[(k + 1) * 64 + n];
        u32 h0 = bf16_rne(w0), h1 = bf16_rne(w1);
        u32 l0 = bf16_rne(w0 - __uint_as_float(h0 << 16));
        u32 l1 = bf16_rne(w1 - __uint_as_float(h1 << 16));
        W2h[i2] = h0 | (h1 << 16);
        W2l[i2] = l0 | (l1 << 16);
    }
}

// ========== GEMM1 (MFMA, LDS-staged W): Hb1 = bf16( (X @ W1) * dis ) ==========
// 2 M-tiles per wave (32 rows). Block covers 128 rows; 64 KB LDS, XOR-swizzled.

__global__ __launch_bounds__(256) void k_gemm1m(
    const float* __restrict__ X, const u32* __restrict__ Wh,
    const u32* __restrict__ Wl, const float* __restrict__ dis,
    u32* __restrict__ Hb, int M)
{
    __shared__ uint4 sW[4096];
    const int tid = threadIdx.x;
    const uint4* Wh4 = (const uint4*)Wh;
    const uint4* Wl4 = (const uint4*)Wl;
#pragma unroll
    for (int i = 0; i < 8; ++i) {
        int idx = tid + i * 256;          // 0..2047
        int l = idx >> 4, j = idx & 15;
        int js = j ^ (l & 7);
        sW[l * 16 + js] = Wh4[idx];
        sW[2048 + l * 16 + js] = Wl4[idx];
    }
    __syncthreads();

    const int w = tid >> 6, lane = tid & 63;
    const int mrow = blockIdx.x * 128 + w * 32;
    const int m16 = lane & 15, quad = lane >> 4;

    frag_u Ah[2][4], Al[2][4];
#pragma unroll
    for (int t = 0; t < 2; ++t) {
        int gm = mrow + t * 16 + m16; if (gm >= M) gm = M - 1;
        const float* xr = X + (size_t)gm * 128;
#pragma unroll
        for (int kt = 0; kt < 4; ++kt) {
            int kb = kt * 32 + quad * 8;
            float4 xa = *(const float4*)(xr + kb);
            float4 xb = *(const float4*)(xr + kb + 4);
            float xe[8] = {xa.x, xa.y, xa.z, xa.w, xb.x, xb.y, xb.z, xb.w};
#pragma unroll
            for (int j = 0; j < 4; ++j) {
                u32 h0 = bf16_rne(xe[2 * j]),     h1 = bf16_rne(xe[2 * j + 1]);
                u32 l0 = bf16_rne(xe[2 * j]     - __uint_as_float(h0 << 16));
                u32 l1 = bf16_rne(xe[2 * j + 1] - __uint_as_float(h1 << 16));
                Ah[t][kt].u[j] = h0 | (h1 << 16);
                Al[t][kt].u[j] = l0 | (l1 << 16);
            }
        }
    }

    float dv[2][4];
#pragma unroll
    for (int t = 0; t < 2; ++t)
#pragma unroll
        for (int r = 0; r < 4; ++r) {
            int gR = mrow + t * 16 + quad * 4 + r;
            dv[t][r] = (gR < M) ? dis[gR] : 0.f;
        }

#pragma unroll
    for (int nt = 0; nt < 8; ++nt) {
        f32x4 acc0 = {0.f, 0.f, 0.f, 0.f};
        f32x4 acc1 = {0.f, 0.f, 0.f, 0.f};
        int l = nt * 16 + m16;
        int swz = l & 7;
#pragma unroll
        for (int kt = 0; kt < 4; ++kt) {
            frag_u Bh, Bl;
            int jb = (kt * 4 + quad) ^ swz;
            Bh.q = sW[l * 16 + jb];
            Bl.q = sW[2048 + l * 16 + jb];
            acc0 = __builtin_amdgcn_mfma_f32_16x16x32_bf16(Al[0][kt].v, Bh.v, acc0, 0, 0, 0);
            acc0 = __builtin_amdgcn_mfma_f32_16x16x32_bf16(Ah[0][kt].v, Bl.v, acc0, 0, 0, 0);
            acc0 = __builtin_amdgcn_mfma_f32_16x16x32_bf16(Ah[0][kt].v, Bh.v, acc0, 0, 0, 0);
            acc1 = __builtin_amdgcn_mfma_f32_16x16x32_bf16(Al[1][kt].v, Bh.v, acc1, 0, 0, 0);
            acc1 = __builtin_amdgcn_mfma_f32_16x16x32_bf16(Ah[1][kt].v, Bl.v, acc1, 0, 0, 0);
            acc1 = __builtin_amdgcn_mfma_f32_16x16x32_bf16(Ah[1][kt].v, Bh.v, acc1, 0, 0, 0);
        }
#pragma unroll
        for (int r = 0; r < 4; ++r) {
            float vs0 = acc0[r] * dv[0][r];
            float vo0 = __shfl_xor(vs0, 1, 64);
            float vs1 = acc1[r] * dv[1][r];
            float vo1 = __shfl_xor(vs1, 1, 64);
            if ((m16 & 1) == 0) {
                int gR0 = mrow + quad * 4 + r;
                if (gR0 < M)
                    Hb[(size_t)gR0 * 64 + nt * 8 + (m16 >> 1)] =
                        bf16_rne(vs0) | (bf16_rne(vo0) << 16);
                int gR1 = mrow + 16 + quad * 4 + r;
                if (gR1 < M)
                    Hb[(size_t)gR1 * 64 + nt * 8 + (m16 >> 1)] =
                        bf16_rne(vs1) | (bf16_rne(vo1) << 16);
            }
        }
    }
}

// ============================================================================
// Fused agg1(both halves) -> gemm2: block-local dependency only (gemm2 row r
// needs only agg1 row r), so LDS handoff replaces the agg1b global round-trip
// (26 MB write + 26 MB read) and two kernel boundaries. NO grid sync needed.
// Block = 256 threads owns 64 nodes; LDS 16 KB (>=6 blocks/CU resident).
// Agg body == proven k_aggh; gemm2 body == proven R7 phase-B (absmax-verified).
// W2 hi/lo read from global (32 KB, L2-hot).
// ============================================================================

__global__ __launch_bounds__(256) void k_agg1g2(
    const int* __restrict__ rowptr, const int* __restrict__ csr,
    const float* __restrict__ dis, const u32* __restrict__ Hb1,
    const float* __restrict__ b1,
    const u32* __restrict__ W2h, const u32* __restrict__ W2l,
    u32* __restrict__ Hb2, int N)
{
    __shared__ uint4 sH[1024];         // 64 rows x 16 uint4 (XOR-swizzled), 16 KB
    const int tid = threadIdx.x;
    const int n0 = blockIdx.x * 64;
    const char* hb = (const char*)Hb1;
    const int grp = tid >> 3, li = tid & 7;

    // ---- agg1 phase: 128 (node,half) tasks over 32 groups of 8 lanes ----
    for (int it = 0; it < 4; ++it) {
        int task = it * 32 + grp;      // 0..127
        int half = task & 1;
        int nl = task >> 1;            // 0..63
        int n = n0 + nl;
        uint4 p = make_uint4(0u, 0u, 0u, 0u);
        if (n < N) {
            int e = rowptr[n];
            int s1 = rowptr[n + 1];
            const float dn = dis[n];
            const u32 off = (u32)(half * 128 + li * 16);

            f32x2 acc[4];
#pragma unroll
            for (int j = 0; j < 4; ++j) acc[j] = 0.f;

            for (; e + 8 <= s1; e += 8) {
                u32 a0 = (u32)csr[e + 0] << 8; u32 a1 = (u32)csr[e + 1] << 8;
                u32 a2 = (u32)csr[e + 2] << 8; u32 a3 = (u32)csr[e + 3] << 8;
                u32 a4 = (u32)csr[e + 4] << 8; u32 a5 = (u32)csr[e + 5] << 8;
                u32 a6 = (u32)csr[e + 6] << 8; u32 a7 = (u32)csr[e + 7] << 8;
                uint4 q0 = *(const uint4*)(hb + a0 + off);
                uint4 q1 = *(const uint4*)(hb + a1 + off);
                uint4 q2 = *(const uint4*)(hb + a2 + off);
                uint4 q3 = *(const uint4*)(hb + a3 + off);
                uint4 q4 = *(const uint4*)(hb + a4 + off);
                uint4 q5 = *(const uint4*)(hb + a5 + off);
                uint4 q6 = *(const uint4*)(hb + a6 + off);
                uint4 q7 = *(const uint4*)(hb + a7 + off);
                add8p(acc, q0); add8p(acc, q1); add8p(acc, q2); add8p(acc, q3);
                add8p(acc, q4); add8p(acc, q5); add8p(acc, q6); add8p(acc, q7);
            }
            for (; e + 2 <= s1; e += 2) {
                u32 a0 = (u32)csr[e + 0] << 8; u32 a1 = (u32)csr[e + 1] << 8;
                uint4 q0 = *(const uint4*)(hb + a0 + off);
                uint4 q1 = *(const uint4*)(hb + a1 + off);
                add8p(acc, q0); add8p(acc, q1);
            }
            if (e < s1) {
                u32 a0 = (u32)csr[e] << 8;
                uint4 q0 = *(const uint4*)(hb + a0 + off);
                add8p(acc, q0);
            }
            {   // self-loop: + own (already dis-scaled) row
                uint4 q = *(const uint4*)(hb + ((u32)n << 8) + off);
                add8p(acc, q);
            }

            float4 bb0 = ((const float4*)b1)[(half * 128 + li * 16) >> 3];
            float4 bb1 = ((const float4*)b1)[((half * 128 + li * 16) >> 3) + 1];
            p.x = bf16_rne(fmaf(dn, acc[0].x, bb0.x)) | (bf16_rne(fmaf(dn, acc[0].y, bb0.y)) << 16);
            p.y = bf16_rne(fmaf(dn, acc[1].x, bb0.z)) | (bf16_rne(fmaf(dn, acc[1].y, bb0.w)) << 16);
            p.z = bf16_rne(fmaf(dn, acc[2].x, bb1.x)) | (bf16_rne(fmaf(dn, acc[2].y, bb1.y)) << 16);
            p.w = bf16_rne(fmaf(dn, acc[3].x, bb1.z)) | (bf16_rne(fmaf(dn, acc[3].y, bb1.w)) << 16);
        }
        sH[nl * 16 + ((half * 8 + li) ^ (nl & 7))] = p;
    }
    __syncthreads();

    // ---- gemm2 phase: Hb2 rows [n0, n0+64), 1 M-tile per wave ----
    {
        const int w = tid >> 6, lane = tid & 63;
        const int m16 = lane & 15, quad = lane >> 4;
        const uint4* Wh4 = (const uint4*)W2h;
        const uint4* Wl4 = (const uint4*)W2l;
        const int mrow = n0 + w * 16;
        const int gl = w * 16 + m16;   // local row 0..63

        frag_u A[4];
#pragma unroll
        for (int kt = 0; kt < 4; ++kt) {
            A[kt].q = sH[gl * 16 + ((kt * 4 + quad) ^ (gl & 7))];
#pragma unroll
            for (int j = 0; j < 4; ++j) A[kt].u[j] = relu_pk(A[kt].u[j]);
        }

        float dv[4];
#pragma unroll
        for (int r = 0; r < 4; ++r) {
            int gR = mrow + quad * 4 + r;
            dv[r] = (gR < N) ? dis[gR] : 0.f;
        }

#pragma unroll
        for (int nt = 0; nt < 4; ++nt) {
            f32x4 acc = {0.f, 0.f, 0.f, 0.f};
            int l = nt * 16 + m16;
#pragma unroll
            for (int kt = 0; kt < 4; ++kt) {
                frag_u Bh, Bl;
                Bh.q = Wh4[l * 16 + kt * 4 + quad];
                Bl.q = Wl4[l * 16 + kt * 4 + quad];
                acc = __builtin_amdgcn_mfma_f32_16x16x32_bf16(A[kt].v, Bl.v, acc, 0, 0, 0);
                acc = __builtin_amdgcn_mfma_f32_16x16x32_bf16(A[kt].v, Bh.v, acc, 0, 0, 0);
            }
#pragma unroll
            for (int r = 0; r < 4; ++r) {
                float vs = acc[r] * dv[r];
                float vo = __shfl_xor(vs, 1, 64);
                if ((m16 & 1) == 0) {
                    int gR = mrow + quad * 4 + r;
                    if (gR < N)
                        Hb2[(size_t)gR * 32 + nt * 8 + (m16 >> 1)] =
                            bf16_rne(vs) | (bf16_rne(vo) << 16);
                }
            }
        }
    }
}

// ====== Aggregate L2: 8-lane group per node, 16B/lane, zero shuffles ======

template <int SH, int POFF>
__global__ __launch_bounds__(256) void k_aggh(
    const int* __restrict__ rowptr, const int* __restrict__ csr,
    const float* __restrict__ dis, const u32* __restrict__ Hb,
    const float* __restrict__ bias, u32* __restrict__ AGGb, int N)
{
    int gid = blockIdx.x * 256 + threadIdx.x;
    int n = gid >> 3;
    int li = threadIdx.x & 7;
    if (n >= N) return;
    int e = rowptr[n];
    int s1 = rowptr[n + 1];
    const float dn = dis[n];
    const char* hb = (const char*)Hb;
    const u32 off = (u32)(POFF + li * 16);

    f32x2 acc[4];
#pragma unroll
    for (int j = 0; j < 4; ++j) acc[j] = 0.f;

    for (; e + 8 <= s1; e += 8) {
        u32 a0 = (u32)csr[e + 0] << SH; u32 a1 = (u32)csr[e + 1] << SH;
        u32 a2 = (u32)csr[e + 2] << SH; u32 a3 = (u32)csr[e + 3] << SH;
        u32 a4 = (u32)csr[e + 4] << SH; u32 a5 = (u32)csr[e + 5] << SH;
        u32 a6 = (u32)csr[e + 6] << SH; u32 a7 = (u32)csr[e + 7] << SH;
        uint4 q0 = *(const uint4*)(hb + a0 + off);
        uint4 q1 = *(const uint4*)(hb + a1 + off);
        uint4 q2 = *(const uint4*)(hb + a2 + off);
        uint4 q3 = *(const uint4*)(hb + a3 + off);
        uint4 q4 = *(const uint4*)(hb + a4 + off);
        uint4 q5 = *(const uint4*)(hb + a5 + off);
        uint4 q6 = *(const uint4*)(hb + a6 + off);
        uint4 q7 = *(const uint4*)(hb + a7 + off);
        add8p(acc, q0); add8p(acc, q1); add8p(acc, q2); add8p(acc, q3);
        add8p(acc, q4); add8p(acc, q5); add8p(acc, q6); add8p(acc, q7);
    }
    for (; e + 2 <= s1; e += 2) {
        u32 a0 = (u32)csr[e + 0] << SH; u32 a1 = (u32)csr[e + 1] << SH;
        uint4 q0 = *(const uint4*)(hb + a0 + off);
        uint4 q1 = *(const uint4*)(hb + a1 + off);
        add8p(acc, q0); add8p(acc, q1);
    }
    if (e < s1) {
        u32 a0 = (u32)csr[e] << SH;
        uint4 q0 = *(const uint4*)(hb + a0 + off);
        add8p(acc, q0);
    }
    {   // self-loop: + own (already dis-scaled) row
        uint4 q = *(const uint4*)(hb + ((u32)n << SH) + off);
        add8p(acc, q);
    }

    float4 bb0 = ((const float4*)bias)[POFF / 8 + li * 2 + 0];
    float4 bb1 = ((const float4*)bias)[POFF / 8 + li * 2 + 1];
    uint4 p;
    p.x = bf16_rne(fmaf(dn, acc[0].x, bb0.x)) | (bf16_rne(fmaf(dn, acc[0].y, bb0.y)) << 16);
    p.y = bf16_rne(fmaf(dn, acc[1].x, bb0.z)) | (bf16_rne(fmaf(dn, acc[1].y, bb0.w)) << 16);
    p.z = bf16_rne(fmaf(dn, acc[2].x, bb1.x)) | (bf16_rne(fmaf(dn, acc[2].y, bb1.y)) << 16);
    p.w = bf16_rne(fmaf(dn, acc[3].x, bb1.z)) | (bf16_rne(fmaf(dn, acc[3].y, bb1.w)) << 16);
    ((uint4*)AGGb)[(size_t)n * (1 << (SH - 4)) + POFF / 16 + li] = p;
}

// ========= mean pool over sorted batch (bf16 input) + fused classifier =========

__device__ inline int lower_bound(const int* __restrict__ b, int n, int v) {
    int lo = 0, hi = n;
    while (lo < hi) { int m = (lo + hi) >> 1; if (b[m] < v) lo = m + 1; else hi = m; }
    return lo;
}

__global__ __launch_bounds__(256) void k_poolfc(
    const int* __restrict__ batch, const u32* __restrict__ AGGb2,
    const float* __restrict__ Wfc, const float* __restrict__ bfc,
    float* __restrict__ out, int n)
{
    int g = blockIdx.x;
    int start = lower_bound(batch, n, g);
    int end   = lower_bound(batch, n, g + 1);
    int tid = threadIdx.x;
    int f = tid & 63, stripe = tid >> 6;
    int ui = f >> 1, hi = f & 1;
    float acc = 0.f;
    for (int i = start + stripe; i < end; i += 4) {
        u32 v = AGGb2[(size_t)i * 32 + ui];
        acc += hi ? bf_hi(v) : bf_lo(v);
    }
    __shared__ float red[256];
    __shared__ float mean[64];
    red[tid] = acc;
    __syncthreads();
    if (tid < 64) {
        float s = red[tid] + red[tid + 64] + red[tid + 128] + red[tid + 192];
        float c = (float)(end - start);
        mean[tid] = s / fmaxf(c, 1.0f);
    }
    __syncthreads();
    if (tid < 10) {
        float o = bfc[tid];
        for (int k = 0; k < 64; ++k)
            o = fmaf(mean[k], Wfc[k * 10 + tid], o);
        out[g * 10 + tid] = o;
    }
}

// ================= launch =================

extern "C" void kernel_launch(void* const* d_in, const int* in_sizes, int n_in,
                              void* d_out, int out_size, void* d_ws, size_t ws_size,
                              hipStream_t stream)
{
    const float* x    = (const float*)d_in[0];
    const int*   ei   = (const int*)d_in[1];
    const int*   batch= (const int*)d_in[2];
    const float* W1   = (const float*)d_in[3];
    const float* b1   = (const float*)d_in[4];
    const float* W2   = (const float*)d_in[5];
    const float* b2   = (const float*)d_in[6];
    const float* Wfc  = (const float*)d_in[7];
    const float* bfc  = (const float*)d_in[8];
    float* out = (float*)d_out;

    const int N  = in_sizes[0] / 128;     // 100000
    const int E  = in_sizes[1] / 2;       // 3200000
    const int ng = out_size / 10;         // 256

    const int NBK = (N + BKW - 1) / BKW;  // 391 buckets

    // ---- workspace layout (words) ----
    int*   rowptr    = (int*)d_ws;                          // 102400 (N+1)
    int*   bucketCur = rowptr + 102400;                     // 512
    float* dis       = (float*)(bucketCur + 512);           // 102400
    int*   csr       = (int*)(dis + 102400);                // E
    // region A: tmp (NBK*CAP=3.60M) aliases Hb1 (N*64) and agg2b (N*32)
    u32*   tmp       = (u32*)(csr + E);
    u32*   Hb1       = tmp;
    u32*   agg2b    = (u32*)((int*)tmp + (size_t)N * 64);       // N*32 u32
    u16*   Hb2       = (u16*)((int*)agg2b + (size_t)N * 32);    // N*64 u16
    u32*   W1h       = (u32*)((int*)Hb2 + (size_t)N * 32);      // 8192
    u32*   W1l       = W1h + 8192;                              // 8192
    u32*   W2h       = W1l + 8192;                              // 4096
    u32*   W2l       = W2h + 4096;                              // 4096

    // ---- weight convert (+ bucketCur zero) + CSR build ----
    k_convW<<<48, 256, 0, stream>>>(W1, W2, W1h, W1l, W2h, W2l, bucketCur, NBK);
    k_part1<<<(E + TILE1 - 1) / TILE1, 512, 0, stream>>>(ei, bucketCur, tmp, E, N, NBK);
    k_part2<<<NBK, 512, 0, stream>>>(bucketCur, tmp, csr, rowptr, dis, N, NBK);

    // ---- layer 1 GEMM ----
    k_gemm1m<<<(N + 127) / 128, 256, 0, stream>>>(x, W1h, W1l, dis, Hb1, N);

    // ---- fused agg1(both halves) + gemm2 (LDS handoff, no agg1b) ----
    k_agg1g2<<<(N + 63) / 64, 256, 0, stream>>>(rowptr, csr, dis, Hb1, b1,
                                                W2h, W2l, (u32*)Hb2, N);

    // ---- layer 2 aggregate ----
    k_aggh<7, 0><<<(N * 8 + 255) / 256, 256, 0, stream>>>(rowptr, csr, dis,
                                                          (const u32*)Hb2, b2, agg2b, N);

    // ---- pool + classifier (fused) ----
    k_poolfc<<<ng, 256, 0, stream>>>(batch, agg2b, Wfc, bfc, out, N);
}

// Round 10
// 382.618 us; speedup vs baseline: 1.8359x; 1.0553x over previous
//
#include <hip/hip_runtime.h>
#include <math.h>

typedef unsigned int  u32;
typedef unsigned short u16;

#define TILE1 8192      // edges per pass-1 block (16/thread @ 512 threads)
#define BKW   256       // nodes per bucket (shift 8)
#define CAP   9216      // tmp slots per bucket (mean 8192, +11 sigma)

typedef __attribute__((ext_vector_type(8))) short bf16x8;
typedef __attribute__((ext_vector_type(4))) float f32x4;
typedef __attribute__((ext_vector_type(2))) float f32x2;
union frag_u { bf16x8 v; u32 u[4]; uint4 q; };

__device__ inline u32 bf16_rne(float f) {
    u32 u = __float_as_uint(f);
    return (u + 0x7FFFu + ((u >> 16) & 1u)) >> 16;
}
__device__ inline float bf_lo(u32 u) { return __uint_as_float(u << 16); }
__device__ inline float bf_hi(u32 u) { return __uint_as_float(u & 0xFFFF0000u); }

__device__ inline f32x2 up2(u32 u) {
    f32x2 t;
    t.x = __uint_as_float(u << 16);
    t.y = __uint_as_float(u & 0xFFFF0000u);
    return t;
}
__device__ inline void add8p(f32x2* a, uint4 q) {
    a[0] += up2(q.x); a[1] += up2(q.y); a[2] += up2(q.z); a[3] += up2(q.w);
}

// relu on packed bf16x2: clear halves whose sign bit is set
__device__ inline u32 relu_pk(u32 v) {
    u32 s = v & 0x80008000u;
    u32 m = (s >> 15) * 0xFFFFu;
    return v & ~m;
}

// ================= CSR build: 2-pass radix partition =================

__global__ __launch_bounds__(512) void k_part1(const int* __restrict__ ei,
                                               int* __restrict__ bucketCur,
                                               u32* __restrict__ tmp,
                                               int E, int N, int NBK) {
    __shared__ int hist[2048];    // 4 replicas for count; [0:512) reused as cursor
    __shared__ int base[512];
    const int tid = threadIdx.x;
    if (tid < NBK) {
        hist[tid] = 0; hist[512 + tid] = 0;
        hist[1024 + tid] = 0; hist[1536 + tid] = 0;
    }
    __syncthreads();

    const int rep = (tid & 3) << 9;
    const int t0 = blockIdx.x * TILE1;
    const int4* ei4s = (const int4*)ei;             // E % 4 == 0
    const int4* ei4d = (const int4*)(ei + E);
    const int q0 = t0 >> 2;
    const int QE = E >> 2;

    int sv[16], dv[16], key[16];
#pragma unroll
    for (int j = 0; j < 4; ++j) {
        int qi = q0 + j * 512 + tid;
        int4 s4 = make_int4(0, 0, 0, 0), d4 = make_int4(-1, -1, -1, -1);
        if (qi < QE) { s4 = ei4s[qi]; d4 = ei4d[qi]; }
        sv[4 * j + 0] = s4.x; dv[4 * j + 0] = d4.x;
        sv[4 * j + 1] = s4.y; dv[4 * j + 1] = d4.y;
        sv[4 * j + 2] = s4.z; dv[4 * j + 2] = d4.z;
        sv[4 * j + 3] = s4.w; dv[4 * j + 3] = d4.w;
    }
#pragma unroll
    for (int j = 0; j < 16; ++j) {
        key[j] = -1;
        if ((unsigned)dv[j] < (unsigned)N && (unsigned)sv[j] < (unsigned)N) {
            key[j] = dv[j] >> 8;
            atomicAdd(&hist[key[j] + rep], 1);
        }
    }
    __syncthreads();
    if (tid < NBK) {
        int tot = hist[tid] + hist[512 + tid] + hist[1024 + tid] + hist[1536 + tid];
        base[tid] = atomicAdd(&bucketCur[tid], tot);
        hist[tid] = 0;                 // running cursor for placement
    }
    __syncthreads();
#pragma unroll
    for (int j = 0; j < 16; ++j) {
        if (key[j] >= 0) {
            int slot = atomicAdd(&hist[key[j]], 1);
            int off = base[key[j]] + slot;
            if (off < CAP)
                tmp[(size_t)key[j] * CAP + off] =
                    ((u32)(dv[j] & 255) << 17) | (u32)sv[j];
        }
    }
}

__global__ __launch_bounds__(512) void k_part2(const int* __restrict__ bucketCnt,
                                               const u32* __restrict__ tmp,
                                               int* __restrict__ csr,
                                               int* __restrict__ rowptr,
                                               float* __restrict__ dis,
                                               int N, int NBK) {
    __shared__ int hist[256];
    __shared__ int ts[512];
    __shared__ int sStart;
    const int b = blockIdx.x;
    const int t = threadIdx.x;

    int myCnt = (t < NBK) ? bucketCnt[t] : 0;
    ts[t] = myCnt;
    __syncthreads();
    for (int off = 1; off < 512; off <<= 1) {
        int u = (t >= off) ? ts[t - off] : 0;
        __syncthreads();
        ts[t] += u;
        __syncthreads();
    }
    if (t == b) sStart = ts[t] - myCnt;
    if (b == 0 && t == NBK - 1) rowptr[N] = ts[t];
    __syncthreads();
    const int start = sStart;
    const int cnt = bucketCnt[b];
    const u32* src = tmp + (size_t)b * CAP;

    if (t < 256) hist[t] = 0;
    __syncthreads();
    for (int i = t; i < cnt; i += 512)
        atomicAdd(&hist[src[i] >> 17], 1);
    __syncthreads();

    int h = (t < 256) ? hist[t] : 0;
    ts[t] = h;
    __syncthreads();
    for (int off = 1; off < 512; off <<= 1) {
        int u = (t >= off) ? ts[t - off] : 0;
        __syncthreads();
        ts[t] += u;
        __syncthreads();
    }
    if (t < 256) hist[t] = ts[t] - h;       // exclusive
    __syncthreads();

    if (t < 256) {
        int gn = (b << 8) + t;
        if (gn < N) {
            int e0 = hist[t];
            int e1 = (t < 255) ? hist[t + 1] : cnt;
            rowptr[gn] = start + e0;
            dis[gn] = rsqrtf((float)(e1 - e0) + 1.0f);
        }
    }
    __syncthreads();

    for (int i = t; i < cnt; i += 512) {
        u32 v = src[i];
        int p = atomicAdd(&hist[v >> 17], 1);
        csr[start + p] = (int)(v & 0x1FFFFu);
    }
}

// ========== weight convert (+ bucketCur zero): n-major bf16 hi/lo tables ==========

__global__ __launch_bounds__(256) void k_convW(
    const float* __restrict__ W1, const float* __restrict__ W2,
    u32* __restrict__ W1h, u32* __restrict__ W1l,
    u32* __restrict__ W2h, u32* __restrict__ W2l,
    int* __restrict__ bucketCur, int NBK)
{
    int idx = blockIdx.x * 256 + threadIdx.x;
    if (idx < NBK) bucketCur[idx] = 0;
    if (idx < 8192) {
        int n = idx >> 6, k = (idx & 63) * 2;
        float w0 = W1[k * 128 + n], w1 = W1[(k + 1) * 128 + n];
        u32 h0 = bf16_rne(w0), h1 = bf16_rne(w1);
        u32 l0 = bf16_rne(w0 - __uint_as_float(h0 << 16));
        u32 l1 = bf16_rne(w1 - __uint_as_float(h1 << 16));
        W1h[idx] = h0 | (h1 << 16);
        W1l[idx] = l0 | (l1 << 16);
    } else if (idx < 12288) {
        int i2 = idx - 8192;
        int n = i2 >> 6, k = (i2 & 63) * 2;
        float w0 = W2[k * 64 + n], w1 = W2[(k + 1) * 64 + n];
        u32 h0 = bf16_rne(w0), h1 = bf16_rne(w1);
        u32 l0 = bf16_rne(w0 - __uint_as_float(h0 << 16));
        u32 l1 = bf16_rne(w1 - __uint_as_float(h1 << 16));
        W2h[i2] = h0 | (h1 << 16);
        W2l[i2] = l0 | (l1 << 16);
    }
}

// ========== GEMM1 (MFMA, LDS-staged W): Hb1 = bf16( (X @ W1) * dis ) ==========
// 2 M-tiles per wave (32 rows). Block covers 128 rows; 64 KB LDS, XOR-swizzled.

__global__ __launch_bounds__(256) void k_gemm1m(
    const float* __restrict__ X, const u32* __restrict__ Wh,
    const u32* __restrict__ Wl, const float* __restrict__ dis,
    u32* __restrict__ Hb, int M)
{
    __shared__ uint4 sW[4096];
    const int tid = threadIdx.x;
    const uint4* Wh4 = (const uint4*)Wh;
    const uint4* Wl4 = (const uint4*)Wl;
#pragma unroll
    for (int i = 0; i < 8; ++i) {
        int idx = tid + i * 256;          // 0..2047
        int l = idx >> 4, j = idx & 15;
        int js = j ^ (l & 7);
        sW[l * 16 + js] = Wh4[idx];
        sW[2048 + l * 16 + js] = Wl4[idx];
    }
    __syncthreads();

    const int w = tid >> 6, lane = tid & 63;
    const int mrow = blockIdx.x * 128 + w * 32;
    const int m16 = lane & 15, quad = lane >> 4;

    frag_u Ah[2][4], Al[2][4];
#pragma unroll
    for (int t = 0; t < 2; ++t) {
        int gm = mrow + t * 16 + m16; if (gm >= M) gm = M - 1;
        const float* xr = X + (size_t)gm * 128;
#pragma unroll
        for (int kt = 0; kt < 4; ++kt) {
            int kb = kt * 32 + quad * 8;
            float4 xa = *(const float4*)(xr + kb);
            float4 xb = *(const float4*)(xr + kb + 4);
            float xe[8] = {xa.x, xa.y, xa.z, xa.w, xb.x, xb.y, xb.z, xb.w};
#pragma unroll
            for (int j = 0; j < 4; ++j) {
                u32 h0 = bf16_rne(xe[2 * j]),     h1 = bf16_rne(xe[2 * j + 1]);
                u32 l0 = bf16_rne(xe[2 * j]     - __uint_as_float(h0 << 16));
                u32 l1 = bf16_rne(xe[2 * j + 1] - __uint_as_float(h1 << 16));
                Ah[t][kt].u[j] = h0 | (h1 << 16);
                Al[t][kt].u[j] = l0 | (l1 << 16);
            }
        }
    }

    float dv[2][4];
#pragma unroll
    for (int t = 0; t < 2; ++t)
#pragma unroll
        for (int r = 0; r < 4; ++r) {
            int gR = mrow + t * 16 + quad * 4 + r;
            dv[t][r] = (gR < M) ? dis[gR] : 0.f;
        }

#pragma unroll
    for (int nt = 0; nt < 8; ++nt) {
        f32x4 acc0 = {0.f, 0.f, 0.f, 0.f};
        f32x4 acc1 = {0.f, 0.f, 0.f, 0.f};
        int l = nt * 16 + m16;
        int swz = l & 7;
#pragma unroll
        for (int kt = 0; kt < 4; ++kt) {
            frag_u Bh, Bl;
            int jb = (kt * 4 + quad) ^ swz;
            Bh.q = sW[l * 16 + jb];
            Bl.q = sW[2048 + l * 16 + jb];
            acc0 = __builtin_amdgcn_mfma_f32_16x16x32_bf16(Al[0][kt].v, Bh.v, acc0, 0, 0, 0);
            acc0 = __builtin_amdgcn_mfma_f32_16x16x32_bf16(Ah[0][kt].v, Bl.v, acc0, 0, 0, 0);
            acc0 = __builtin_amdgcn_mfma_f32_16x16x32_bf16(Ah[0][kt].v, Bh.v, acc0, 0, 0, 0);
            acc1 = __builtin_amdgcn_mfma_f32_16x16x32_bf16(Al[1][kt].v, Bh.v, acc1, 0, 0, 0);
            acc1 = __builtin_amdgcn_mfma_f32_16x16x32_bf16(Ah[1][kt].v, Bl.v, acc1, 0, 0, 0);
            acc1 = __builtin_amdgcn_mfma_f32_16x16x32_bf16(Ah[1][kt].v, Bh.v, acc1, 0, 0, 0);
        }
#pragma unroll
        for (int r = 0; r < 4; ++r) {
            float vs0 = acc0[r] * dv[0][r];
            float vo0 = __shfl_xor(vs0, 1, 64);
            float vs1 = acc1[r] * dv[1][r];
            float vo1 = __shfl_xor(vs1, 1, 64);
            if ((m16 & 1) == 0) {
                int gR0 = mrow + quad * 4 + r;
                if (gR0 < M)
                    Hb[(size_t)gR0 * 64 + nt * 8 + (m16 >> 1)] =
                        bf16_rne(vs0) | (bf16_rne(vo0) << 16);
                int gR1 = mrow + 16 + quad * 4 + r;
                if (gR1 < M)
                    Hb[(size_t)gR1 * 64 + nt * 8 + (m16 >> 1)] =
                        bf16_rne(vs1) | (bf16_rne(vo1) << 16);
            }
        }
    }
}

// ========== GEMM2 (MFMA, LDS-staged W): Hb2 = bf16( (relu(agg1b) @ W2) * dis ) ==========
// 2 M-tiles per wave, block covers 128 rows.

__global__ __launch_bounds__(256) void k_gemm2m(
    const u32* __restrict__ Xb, const u32* __restrict__ Wh,
    const u32* __restrict__ Wl, const float* __restrict__ dis,
    u32* __restrict__ Hb, int M)
{
    __shared__ uint4 sW[2176];
    const int tid = threadIdx.x;
    const uint4* Wh4 = (const uint4*)Wh;
    const uint4* Wl4 = (const uint4*)Wl;
#pragma unroll
    for (int i = 0; i < 4; ++i) {
        int idx = tid + i * 256;
        int l = idx >> 4, j = idx & 15;
        sW[l * 17 + j] = Wh4[l * 16 + j];
        sW[1088 + l * 17 + j] = Wl4[l * 16 + j];
    }
    __syncthreads();

    const int w = tid >> 6, lane = tid & 63;
    const int mrow = blockIdx.x * 128 + w * 32;
    const int m16 = lane & 15, quad = lane >> 4;

    const uint4* X4 = (const uint4*)Xb;
    frag_u A[2][4];
#pragma unroll
    for (int t = 0; t < 2; ++t) {
        int gm = mrow + t * 16 + m16; if (gm >= M) gm = M - 1;
#pragma unroll
        for (int kt = 0; kt < 4; ++kt) {
            A[t][kt].q = X4[(size_t)gm * 16 + kt * 4 + quad];
#pragma unroll
            for (int j = 0; j < 4; ++j) A[t][kt].u[j] = relu_pk(A[t][kt].u[j]);
        }
    }

    float dv[2][4];
#pragma unroll
    for (int t = 0; t < 2; ++t)
#pragma unroll
        for (int r = 0; r < 4; ++r) {
            int gR = mrow + t * 16 + quad * 4 + r;
            dv[t][r] = (gR < M) ? dis[gR] : 0.f;
        }

#pragma unroll
    for (int nt = 0; nt < 4; ++nt) {
        f32x4 acc0 = {0.f, 0.f, 0.f, 0.f};
        f32x4 acc1 = {0.f, 0.f, 0.f, 0.f};
        int l = nt * 16 + m16;
#pragma unroll
        for (int kt = 0; kt < 4; ++kt) {
            frag_u Bh, Bl;
            Bh.q = sW[l * 17 + kt * 4 + quad];
            Bl.q = sW[1088 + l * 17 + kt * 4 + quad];
            acc0 = __builtin_amdgcn_mfma_f32_16x16x32_bf16(A[0][kt].v, Bl.v, acc0, 0, 0, 0);
            acc0 = __builtin_amdgcn_mfma_f32_16x16x32_bf16(A[0][kt].v, Bh.v, acc0, 0, 0, 0);
            acc1 = __builtin_amdgcn_mfma_f32_16x16x32_bf16(A[1][kt].v, Bl.v, acc1, 0, 0, 0);
            acc1 = __builtin_amdgcn_mfma_f32_16x16x32_bf16(A[1][kt].v, Bh.v, acc1, 0, 0, 0);
        }
#pragma unroll
        for (int r = 0; r < 4; ++r) {
            float vs0 = acc0[r] * dv[0][r];
            float vo0 = __shfl_xor(vs0, 1, 64);
            float vs1 = acc1[r] * dv[1][r];
            float vo1 = __shfl_xor(vs1, 1, 64);
            if ((m16 & 1) == 0) {
                int gR0 = mrow + quad * 4 + r;
                if (gR0 < M)
                    Hb[(size_t)gR0 * 32 + nt * 8 + (m16 >> 1)] =
                        bf16_rne(vs0) | (bf16_rne(vo0) << 16);
                int gR1 = mrow + 16 + quad * 4 + r;
                if (gR1 < M)
                    Hb[(size_t)gR1 * 32 + nt * 8 + (m16 >> 1)] =
                        bf16_rne(vs1) | (bf16_rne(vo1) << 16);
            }
        }
    }
}

// ====== Aggregate L1 (both halves in one dispatch via blockIdx.y) ======
// 8-lane group per node, 16B/lane, zero shuffles. POFF = blockIdx.y * 128:
// work-identical to R3's two template dispatches, one launch (boundary saved).

__global__ __launch_bounds__(256) void k_agg1(
    const int* __restrict__ rowptr, const int* __restrict__ csr,
    const float* __restrict__ dis, const u32* __restrict__ Hb,
    const float* __restrict__ bias, u32* __restrict__ AGGb, int N)
{
    int gid = blockIdx.x * 256 + threadIdx.x;
    int n = gid >> 3;
    int li = threadIdx.x & 7;
    if (n >= N) return;
    int e = rowptr[n];
    int s1 = rowptr[n + 1];
    const float dn = dis[n];
    const char* hb = (const char*)Hb;
    const u32 POFF = (u32)blockIdx.y << 7;
    const u32 off = POFF + ((u32)li << 4);

    f32x2 acc[4];
#pragma unroll
    for (int j = 0; j < 4; ++j) acc[j] = 0.f;

    for (; e + 8 <= s1; e += 8) {
        u32 a0 = (u32)csr[e + 0] << 8; u32 a1 = (u32)csr[e + 1] << 8;
        u32 a2 = (u32)csr[e + 2] << 8; u32 a3 = (u32)csr[e + 3] << 8;
        u32 a4 = (u32)csr[e + 4] << 8; u32 a5 = (u32)csr[e + 5] << 8;
        u32 a6 = (u32)csr[e + 6] << 8; u32 a7 = (u32)csr[e + 7] << 8;
        uint4 q0 = *(const uint4*)(hb + a0 + off);
        uint4 q1 = *(const uint4*)(hb + a1 + off);
        uint4 q2 = *(const uint4*)(hb + a2 + off);
        uint4 q3 = *(const uint4*)(hb + a3 + off);
        uint4 q4 = *(const uint4*)(hb + a4 + off);
        uint4 q5 = *(const uint4*)(hb + a5 + off);
        uint4 q6 = *(const uint4*)(hb + a6 + off);
        uint4 q7 = *(const uint4*)(hb + a7 + off);
        add8p(acc, q0); add8p(acc, q1); add8p(acc, q2); add8p(acc, q3);
        add8p(acc, q4); add8p(acc, q5); add8p(acc, q6); add8p(acc, q7);
    }
    for (; e + 2 <= s1; e += 2) {
        u32 a0 = (u32)csr[e + 0] << 8; u32 a1 = (u32)csr[e + 1] << 8;
        uint4 q0 = *(const uint4*)(hb + a0 + off);
        uint4 q1 = *(const uint4*)(hb + a1 + off);
        add8p(acc, q0); add8p(acc, q1);
    }
    if (e < s1) {
        u32 a0 = (u32)csr[e] << 8;
        uint4 q0 = *(const uint4*)(hb + a0 + off);
        add8p(acc, q0);
    }
    {   // self-loop: + own (already dis-scaled) row
        uint4 q = *(const uint4*)(hb + ((u32)n << 8) + off);
        add8p(acc, q);
    }

    float4 bb0 = ((const float4*)bias)[off >> 3];
    float4 bb1 = ((const float4*)bias)[(off >> 3) + 1];
    uint4 p;
    p.x = bf16_rne(fmaf(dn, acc[0].x, bb0.x)) | (bf16_rne(fmaf(dn, acc[0].y, bb0.y)) << 16);
    p.y = bf16_rne(fmaf(dn, acc[1].x, bb0.z)) | (bf16_rne(fmaf(dn, acc[1].y, bb0.w)) << 16);
    p.z = bf16_rne(fmaf(dn, acc[2].x, bb1.x)) | (bf16_rne(fmaf(dn, acc[2].y, bb1.y)) << 16);
    p.w = bf16_rne(fmaf(dn, acc[3].x, bb1.z)) | (bf16_rne(fmaf(dn, acc[3].y, bb1.w)) << 16);
    ((uint4*)AGGb)[(size_t)n * 16 + (off >> 4)] = p;
}

// ====== Aggregate L2 (D=64): 8-lane group per node ======

__global__ __launch_bounds__(256) void k_agg2(
    const int* __restrict__ rowptr, const int* __restrict__ csr,
    const float* __restrict__ dis, const u32* __restrict__ Hb,
    const float* __restrict__ bias, u32* __restrict__ AGGb, int N)
{
    int gid = blockIdx.x * 256 + threadIdx.x;
    int n = gid >> 3;
    int li = threadIdx.x & 7;
    if (n >= N) return;
    int e = rowptr[n];
    int s1 = rowptr[n + 1];
    const float dn = dis[n];
    const char* hb = (const char*)Hb;
    const u32 off = (u32)li << 4;

    f32x2 acc[4];
#pragma unroll
    for (int j = 0; j < 4; ++j) acc[j] = 0.f;

    for (; e + 8 <= s1; e += 8) {
        u32 a0 = (u32)csr[e + 0] << 7; u32 a1 = (u32)csr[e + 1] << 7;
        u32 a2 = (u32)csr[e + 2] << 7; u32 a3 = (u32)csr[e + 3] << 7;
        u32 a4 = (u32)csr[e + 4] << 7; u32 a5 = (u32)csr[e + 5] << 7;
        u32 a6 = (u32)csr[e + 6] << 7; u32 a7 = (u32)csr[e + 7] << 7;
        uint4 q0 = *(const uint4*)(hb + a0 + off);
        uint4 q1 = *(const uint4*)(hb + a1 + off);
        uint4 q2 = *(const uint4*)(hb + a2 + off);
        uint4 q3 = *(const uint4*)(hb + a3 + off);
        uint4 q4 = *(const uint4*)(hb + a4 + off);
        uint4 q5 = *(const uint4*)(hb + a5 + off);
        uint4 q6 = *(const uint4*)(hb + a6 + off);
        uint4 q7 = *(const uint4*)(hb + a7 + off);
        add8p(acc, q0); add8p(acc, q1); add8p(acc, q2); add8p(acc, q3);
        add8p(acc, q4); add8p(acc, q5); add8p(acc, q6); add8p(acc, q7);
    }
    for (; e + 2 <= s1; e += 2) {
        u32 a0 = (u32)csr[e + 0] << 7; u32 a1 = (u32)csr[e + 1] << 7;
        uint4 q0 = *(const uint4*)(hb + a0 + off);
        uint4 q1 = *(const uint4*)(hb + a1 + off);
        add8p(acc, q0); add8p(acc, q1);
    }
    if (e < s1) {
        u32 a0 = (u32)csr[e] << 7;
        uint4 q0 = *(const uint4*)(hb + a0 + off);
        add8p(acc, q0);
    }
    {   // self-loop
        uint4 q = *(const uint4*)(hb + ((u32)n << 7) + off);
        add8p(acc, q);
    }

    float4 bb0 = ((const float4*)bias)[li * 2 + 0];
    float4 bb1 = ((const float4*)bias)[li * 2 + 1];
    uint4 p;
    p.x = bf16_rne(fmaf(dn, acc[0].x, bb0.x)) | (bf16_rne(fmaf(dn, acc[0].y, bb0.y)) << 16);
    p.y = bf16_rne(fmaf(dn, acc[1].x, bb0.z)) | (bf16_rne(fmaf(dn, acc[1].y, bb0.w)) << 16);
    p.z = bf16_rne(fmaf(dn, acc[2].x, bb1.x)) | (bf16_rne(fmaf(dn, acc[2].y, bb1.y)) << 16);
    p.w = bf16_rne(fmaf(dn, acc[3].x, bb1.z)) | (bf16_rne(fmaf(dn, acc[3].y, bb1.w)) << 16);
    ((uint4*)AGGb)[(size_t)n * 8 + li] = p;
}

// ========= mean pool over sorted batch (bf16 input) + fused classifier =========

__device__ inline int lower_bound(const int* __restrict__ b, int n, int v) {
    int lo = 0, hi = n;
    while (lo < hi) { int m = (lo + hi) >> 1; if (b[m] < v) lo = m + 1; else hi = m; }
    return lo;
}

__global__ __launch_bounds__(256) void k_poolfc(
    const int* __restrict__ batch, const u32* __restrict__ AGGb2,
    const float* __restrict__ Wfc, const float* __restrict__ bfc,
    float* __restrict__ out, int n)
{
    int g = blockIdx.x;
    int start = lower_bound(batch, n, g);
    int end   = lower_bound(batch, n, g + 1);
    int tid = threadIdx.x;
    int f = tid & 63, stripe = tid >> 6;
    int ui = f >> 1, hi = f & 1;
    float acc = 0.f;
    for (int i = start + stripe; i < end; i += 4) {
        u32 v = AGGb2[(size_t)i * 32 + ui];
        acc += hi ? bf_hi(v) : bf_lo(v);
    }
    __shared__ float red[256];
    __shared__ float mean[64];
    red[tid] = acc;
    __syncthreads();
    if (tid < 64) {
        float s = red[tid] + red[tid + 64] + red[tid + 128] + red[tid + 192];
        float c = (float)(end - start);
        mean[tid] = s / fmaxf(c, 1.0f);
    }
    __syncthreads();
    if (tid < 10) {
        float o = bfc[tid];
        for (int k = 0; k < 64; ++k)
            o = fmaf(mean[k], Wfc[k * 10 + tid], o);
        out[g * 10 + tid] = o;
    }
}

// ================= launch =================

extern "C" void kernel_launch(void* const* d_in, const int* in_sizes, int n_in,
                              void* d_out, int out_size, void* d_ws, size_t ws_size,
                              hipStream_t stream)
{
    const float* x    = (const float*)d_in[0];
    const int*   ei   = (const int*)d_in[1];
    const int*   batch= (const int*)d_in[2];
    const float* W1   = (const float*)d_in[3];
    const float* b1   = (const float*)d_in[4];
    const float* W2   = (const float*)d_in[5];
    const float* b2   = (const float*)d_in[6];
    const float* Wfc  = (const float*)d_in[7];
    const float* bfc  = (const float*)d_in[8];
    float* out = (float*)d_out;

    const int N  = in_sizes[0] / 128;     // 100000
    const int E  = in_sizes[1] / 2;       // 3200000
    const int ng = out_size / 10;         // 256

    const int NBK = (N + BKW - 1) / BKW;  // 391 buckets

    // ---- workspace layout (words) ----
    int*   rowptr    = (int*)d_ws;                          // 102400 (N+1)
    int*   bucketCur = rowptr + 102400;                     // 512
    float* dis       = (float*)(bucketCur + 512);           // 102400
    int*   csr       = (int*)(dis + 102400);                // E
    // region A (6.4M words): tmp (NBK*CAP=3.60M) -> Hb1 (N*64) -> agg2b (N*32)
    u32*   tmp       = (u32*)(csr + E);
    u32*   Hb1       = tmp;                                     // aliases tmp (tmp dead)
    u32*   agg2b     = tmp;                                     // aliases Hb1 (dead by agg2)
    u32*   agg1b     = (u32*)((int*)tmp + (size_t)N * 64);      // N*64 u32 (bf16 packed)
    u16*   Hb2       = (u16*)((int*)agg1b + (size_t)N * 128);   // N*64 u16
    u32*   W1h       = (u32*)((int*)Hb2 + (size_t)N * 32);      // 8192
    u32*   W1l       = W1h + 8192;                              // 8192
    u32*   W2h       = W1l + 8192;                              // 4096
    u32*   W2l       = W2h + 4096;                              // 4096

    // ---- weight convert (+ bucketCur zero) + CSR build ----
    k_convW<<<48, 256, 0, stream>>>(W1, W2, W1h, W1l, W2h, W2l, bucketCur, NBK);
    k_part1<<<(E + TILE1 - 1) / TILE1, 512, 0, stream>>>(ei, bucketCur, tmp, E, N, NBK);
    k_part2<<<NBK, 512, 0, stream>>>(bucketCur, tmp, csr, rowptr, dis, N, NBK);

    // ---- layer 1 ----
    k_gemm1m<<<(N + 127) / 128, 256, 0, stream>>>(x, W1h, W1l, dis, Hb1, N);
    k_agg1<<<dim3((N * 8 + 255) / 256, 2), 256, 0, stream>>>(rowptr, csr, dis, Hb1, b1, agg1b, N);

    // ---- layer 2 ----
    k_gemm2m<<<(N + 127) / 128, 256, 0, stream>>>(agg1b, W2h, W2l, dis, (u32*)Hb2, N);
    k_agg2<<<(N * 8 + 255) / 256, 256, 0, stream>>>(rowptr, csr, dis, (const u32*)Hb2, b2, agg2b, N);

    // ---- pool + classifier (fused) ----
    k_poolfc<<<ng, 256, 0, stream>>>(batch, agg2b, Wfc, bfc, out, N);
}

// Round 12
// 338.271 us; speedup vs baseline: 2.0766x; 1.1311x over previous
//
#include <hip/hip_runtime.h>
#include <math.h>

typedef unsigned int  u32;
typedef unsigned short u16;

#define TILE1 8192      // edges per pass-1 block (16/thread @ 512 threads)
#define BKW   256       // nodes per bucket (shift 8)
#define CAP   9216      // tmp slots per bucket (mean 8192, +11 sigma)

typedef __attribute__((ext_vector_type(8))) short bf16x8;
typedef __attribute__((ext_vector_type(4))) float f32x4;
typedef __attribute__((ext_vector_type(2))) float f32x2;
union frag_u { bf16x8 v; u32 u[4]; uint4 q; };

__device__ inline u32 bf16_rne(float f) {
    u32 u = __float_as_uint(f);
    return (u + 0x7FFFu + ((u >> 16) & 1u)) >> 16;
}
__device__ inline float bf_lo(u32 u) { return __uint_as_float(u << 16); }
__device__ inline float bf_hi(u32 u) { return __uint_as_float(u & 0xFFFF0000u); }

__device__ inline f32x2 up2(u32 u) {
    f32x2 t;
    t.x = __uint_as_float(u << 16);
    t.y = __uint_as_float(u & 0xFFFF0000u);
    return t;
}

// ---- fp8 e4m3 (OCP on gfx950) pack/unpack via HW converts ----
// NOTE: the builtin's word selector must be a LITERAL constant (R11 compile
// fail taught this) -> two separate wrappers.
__device__ inline u16 fp8pk(float a, float b) {
    return (u16)(__builtin_amdgcn_cvt_pk_fp8_f32(a, b, 0, false) & 0xFFFF);
}
__device__ inline f32x2 pk8lo(u32 w) {
    f32x2 r = __builtin_amdgcn_cvt_pk_f32_fp8(w, false);
    return r;
}
__device__ inline f32x2 pk8hi(u32 w) {
    f32x2 r = __builtin_amdgcn_cvt_pk_f32_fp8(w, true);
    return r;
}
// 16 fp8 -> 16 f32 accumulate (8 cvt + 8 pk-adds)
__device__ inline void add16p(f32x2* a, uint4 q) {
    a[0] += pk8lo(q.x); a[1] += pk8hi(q.x);
    a[2] += pk8lo(q.y); a[3] += pk8hi(q.y);
    a[4] += pk8lo(q.z); a[5] += pk8hi(q.z);
    a[6] += pk8lo(q.w); a[7] += pk8hi(q.w);
}

// relu on packed bf16x2: clear halves whose sign bit is set
__device__ inline u32 relu_pk(u32 v) {
    u32 s = v & 0x80008000u;
    u32 m = (s >> 15) * 0xFFFFu;
    return v & ~m;
}

// ================= CSR build: 2-pass radix partition =================

__global__ __launch_bounds__(512) void k_part1(const int* __restrict__ ei,
                                               int* __restrict__ bucketCur,
                                               u32* __restrict__ tmp,
                                               int E, int N, int NBK) {
    __shared__ int hist[2048];    // 4 replicas for count; [0:512) reused as cursor
    __shared__ int base[512];
    const int tid = threadIdx.x;
    if (tid < NBK) {
        hist[tid] = 0; hist[512 + tid] = 0;
        hist[1024 + tid] = 0; hist[1536 + tid] = 0;
    }
    __syncthreads();

    const int rep = (tid & 3) << 9;
    const int t0 = blockIdx.x * TILE1;
    const int4* ei4s = (const int4*)ei;             // E % 4 == 0
    const int4* ei4d = (const int4*)(ei + E);
    const int q0 = t0 >> 2;
    const int QE = E >> 2;

    int sv[16], dv[16], key[16];
#pragma unroll
    for (int j = 0; j < 4; ++j) {
        int qi = q0 + j * 512 + tid;
        int4 s4 = make_int4(0, 0, 0, 0), d4 = make_int4(-1, -1, -1, -1);
        if (qi < QE) { s4 = ei4s[qi]; d4 = ei4d[qi]; }
        sv[4 * j + 0] = s4.x; dv[4 * j + 0] = d4.x;
        sv[4 * j + 1] = s4.y; dv[4 * j + 1] = d4.y;
        sv[4 * j + 2] = s4.z; dv[4 * j + 2] = d4.z;
        sv[4 * j + 3] = s4.w; dv[4 * j + 3] = d4.w;
    }
#pragma unroll
    for (int j = 0; j < 16; ++j) {
        key[j] = -1;
        if ((unsigned)dv[j] < (unsigned)N && (unsigned)sv[j] < (unsigned)N) {
            key[j] = dv[j] >> 8;
            atomicAdd(&hist[key[j] + rep], 1);
        }
    }
    __syncthreads();
    if (tid < NBK) {
        int tot = hist[tid] + hist[512 + tid] + hist[1024 + tid] + hist[1536 + tid];
        base[tid] = atomicAdd(&bucketCur[tid], tot);
        hist[tid] = 0;                 // running cursor for placement
    }
    __syncthreads();
#pragma unroll
    for (int j = 0; j < 16; ++j) {
        if (key[j] >= 0) {
            int slot = atomicAdd(&hist[key[j]], 1);
            int off = base[key[j]] + slot;
            if (off < CAP)
                tmp[(size_t)key[j] * CAP + off] =
                    ((u32)(dv[j] & 255) << 17) | (u32)sv[j];
        }
    }
}

__global__ __launch_bounds__(512) void k_part2(const int* __restrict__ bucketCnt,
                                               const u32* __restrict__ tmp,
                                               int* __restrict__ csr,
                                               int* __restrict__ rowptr,
                                               float* __restrict__ dis,
                                               int N, int NBK) {
    __shared__ int hist[256];
    __shared__ int ts[512];
    __shared__ int sStart;
    const int b = blockIdx.x;
    const int t = threadIdx.x;

    int myCnt = (t < NBK) ? bucketCnt[t] : 0;
    ts[t] = myCnt;
    __syncthreads();
    for (int off = 1; off < 512; off <<= 1) {
        int u = (t >= off) ? ts[t - off] : 0;
        __syncthreads();
        ts[t] += u;
        __syncthreads();
    }
    if (t == b) sStart = ts[t] - myCnt;
    if (b == 0 && t == NBK - 1) rowptr[N] = ts[t];
    __syncthreads();
    const int start = sStart;
    const int cnt = bucketCnt[b];
    const u32* src = tmp + (size_t)b * CAP;

    if (t < 256) hist[t] = 0;
    __syncthreads();
    for (int i = t; i < cnt; i += 512)
        atomicAdd(&hist[src[i] >> 17], 1);
    __syncthreads();

    int h = (t < 256) ? hist[t] : 0;
    ts[t] = h;
    __syncthreads();
    for (int off = 1; off < 512; off <<= 1) {
        int u = (t >= off) ? ts[t - off] : 0;
        __syncthreads();
        ts[t] += u;
        __syncthreads();
    }
    if (t < 256) hist[t] = ts[t] - h;       // exclusive
    __syncthreads();

    if (t < 256) {
        int gn = (b << 8) + t;
        if (gn < N) {
            int e0 = hist[t];
            int e1 = (t < 255) ? hist[t + 1] : cnt;
            rowptr[gn] = start + e0;
            dis[gn] = rsqrtf((float)(e1 - e0) + 1.0f);
        }
    }
    __syncthreads();

    for (int i = t; i < cnt; i += 512) {
        u32 v = src[i];
        int p = atomicAdd(&hist[v >> 17], 1);
        csr[start + p] = (int)(v & 0x1FFFFu);
    }
}

// ========== weight convert (+ bucketCur zero): n-major bf16 hi/lo tables ==========

__global__ __launch_bounds__(256) void k_convW(
    const float* __restrict__ W1, const float* __restrict__ W2,
    u32* __restrict__ W1h, u32* __restrict__ W1l,
    u32* __restrict__ W2h, u32* __restrict__ W2l,
    int* __restrict__ bucketCur, int NBK)
{
    int idx = blockIdx.x * 256 + threadIdx.x;
    if (idx < NBK) bucketCur[idx] = 0;
    if (idx < 8192) {
        int n = idx >> 6, k = (idx & 63) * 2;
        float w0 = W1[k * 128 + n], w1 = W1[(k + 1) * 128 + n];
        u32 h0 = bf16_rne(w0), h1 = bf16_rne(w1);
        u32 l0 = bf16_rne(w0 - __uint_as_float(h0 << 16));
        u32 l1 = bf16_rne(w1 - __uint_as_float(h1 << 16));
        W1h[idx] = h0 | (h1 << 16);
        W1l[idx] = l0 | (l1 << 16);
    } else if (idx < 12288) {
        int i2 = idx - 8192;
        int n = i2 >> 6, k = (i2 & 63) * 2;
        float w0 = W2[k * 64 + n], w1 = W2[(k + 1) * 64 + n];
        u32 h0 = bf16_rne(w0), h1 = bf16_rne(w1);
        u32 l0 = bf16_rne(w0 - __uint_as_float(h0 << 16));
        u32 l1 = bf16_rne(w1 - __uint_as_float(h1 << 16));
        W2h[i2] = h0 | (h1 << 16);
        W2l[i2] = l0 | (l1 << 16);
    }
}

// ========== GEMM1 (MFMA, LDS-staged W): Hb1 = fp8( (X @ W1) * dis ) ==========
// 2 M-tiles per wave (32 rows). Block covers 128 rows; 64 KB LDS, XOR-swizzled.
// Output row = 128 fp8 = 128 B.

__global__ __launch_bounds__(256) void k_gemm1m(
    const float* __restrict__ X, const u32* __restrict__ Wh,
    const u32* __restrict__ Wl, const float* __restrict__ dis,
    u16* __restrict__ Hb, int M)
{
    __shared__ uint4 sW[4096];
    const int tid = threadIdx.x;
    const uint4* Wh4 = (const uint4*)Wh;
    const uint4* Wl4 = (const uint4*)Wl;
#pragma unroll
    for (int i = 0; i < 8; ++i) {
        int idx = tid + i * 256;          // 0..2047
        int l = idx >> 4, j = idx & 15;
        int js = j ^ (l & 7);
        sW[l * 16 + js] = Wh4[idx];
        sW[2048 + l * 16 + js] = Wl4[idx];
    }
    __syncthreads();

    const int w = tid >> 6, lane = tid & 63;
    const int mrow = blockIdx.x * 128 + w * 32;
    const int m16 = lane & 15, quad = lane >> 4;

    frag_u Ah[2][4], Al[2][4];
#pragma unroll
    for (int t = 0; t < 2; ++t) {
        int gm = mrow + t * 16 + m16; if (gm >= M) gm = M - 1;
        const float* xr = X + (size_t)gm * 128;
#pragma unroll
        for (int kt = 0; kt < 4; ++kt) {
            int kb = kt * 32 + quad * 8;
            float4 xa = *(const float4*)(xr + kb);
            float4 xb = *(const float4*)(xr + kb + 4);
            float xe[8] = {xa.x, xa.y, xa.z, xa.w, xb.x, xb.y, xb.z, xb.w};
#pragma unroll
            for (int j = 0; j < 4; ++j) {
                u32 h0 = bf16_rne(xe[2 * j]),     h1 = bf16_rne(xe[2 * j + 1]);
                u32 l0 = bf16_rne(xe[2 * j]     - __uint_as_float(h0 << 16));
                u32 l1 = bf16_rne(xe[2 * j + 1] - __uint_as_float(h1 << 16));
                Ah[t][kt].u[j] = h0 | (h1 << 16);
                Al[t][kt].u[j] = l0 | (l1 << 16);
            }
        }
    }

    float dv[2][4];
#pragma unroll
    for (int t = 0; t < 2; ++t)
#pragma unroll
        for (int r = 0; r < 4; ++r) {
            int gR = mrow + t * 16 + quad * 4 + r;
            dv[t][r] = (gR < M) ? dis[gR] : 0.f;
        }

#pragma unroll
    for (int nt = 0; nt < 8; ++nt) {
        f32x4 acc0 = {0.f, 0.f, 0.f, 0.f};
        f32x4 acc1 = {0.f, 0.f, 0.f, 0.f};
        int l = nt * 16 + m16;
        int swz = l & 7;
#pragma unroll
        for (int kt = 0; kt < 4; ++kt) {
            frag_u Bh, Bl;
            int jb = (kt * 4 + quad) ^ swz;
            Bh.q = sW[l * 16 + jb];
            Bl.q = sW[2048 + l * 16 + jb];
            acc0 = __builtin_amdgcn_mfma_f32_16x16x32_bf16(Al[0][kt].v, Bh.v, acc0, 0, 0, 0);
            acc0 = __builtin_amdgcn_mfma_f32_16x16x32_bf16(Ah[0][kt].v, Bl.v, acc0, 0, 0, 0);
            acc0 = __builtin_amdgcn_mfma_f32_16x16x32_bf16(Ah[0][kt].v, Bh.v, acc0, 0, 0, 0);
            acc1 = __builtin_amdgcn_mfma_f32_16x16x32_bf16(Al[1][kt].v, Bh.v, acc1, 0, 0, 0);
            acc1 = __builtin_amdgcn_mfma_f32_16x16x32_bf16(Ah[1][kt].v, Bl.v, acc1, 0, 0, 0);
            acc1 = __builtin_amdgcn_mfma_f32_16x16x32_bf16(Ah[1][kt].v, Bh.v, acc1, 0, 0, 0);
        }
#pragma unroll
        for (int r = 0; r < 4; ++r) {
            float vs0 = acc0[r] * dv[0][r];
            float vo0 = __shfl_xor(vs0, 1, 64);
            float vs1 = acc1[r] * dv[1][r];
            float vo1 = __shfl_xor(vs1, 1, 64);
            if ((m16 & 1) == 0) {
                int gR0 = mrow + quad * 4 + r;
                if (gR0 < M)
                    Hb[(size_t)gR0 * 64 + nt * 8 + (m16 >> 1)] = fp8pk(vs0, vo0);
                int gR1 = mrow + 16 + quad * 4 + r;
                if (gR1 < M)
                    Hb[(size_t)gR1 * 64 + nt * 8 + (m16 >> 1)] = fp8pk(vs1, vo1);
            }
        }
    }
}

// ========== GEMM2 (MFMA, LDS-staged W): Hb2 = fp8( (relu(agg1b) @ W2) * dis ) ==========
// 2 M-tiles per wave, block covers 128 rows. Output row = 64 fp8 = 64 B.

__global__ __launch_bounds__(256) void k_gemm2m(
    const u32* __restrict__ Xb, const u32* __restrict__ Wh,
    const u32* __restrict__ Wl, const float* __restrict__ dis,
    u16* __restrict__ Hb, int M)
{
    __shared__ uint4 sW[2176];
    const int tid = threadIdx.x;
    const uint4* Wh4 = (const uint4*)Wh;
    const uint4* Wl4 = (const uint4*)Wl;
#pragma unroll
    for (int i = 0; i < 4; ++i) {
        int idx = tid + i * 256;
        int l = idx >> 4, j = idx & 15;
        sW[l * 17 + j] = Wh4[l * 16 + j];
        sW[1088 + l * 17 + j] = Wl4[l * 16 + j];
    }
    __syncthreads();

    const int w = tid >> 6, lane = tid & 63;
    const int mrow = blockIdx.x * 128 + w * 32;
    const int m16 = lane & 15, quad = lane >> 4;

    const uint4* X4 = (const uint4*)Xb;
    frag_u A[2][4];
#pragma unroll
    for (int t = 0; t < 2; ++t) {
        int gm = mrow + t * 16 + m16; if (gm >= M) gm = M - 1;
#pragma unroll
        for (int kt = 0; kt < 4; ++kt) {
            A[t][kt].q = X4[(size_t)gm * 16 + kt * 4 + quad];
#pragma unroll
            for (int j = 0; j < 4; ++j) A[t][kt].u[j] = relu_pk(A[t][kt].u[j]);
        }
    }

    float dv[2][4];
#pragma unroll
    for (int t = 0; t < 2; ++t)
#pragma unroll
        for (int r = 0; r < 4; ++r) {
            int gR = mrow + t * 16 + quad * 4 + r;
            dv[t][r] = (gR < M) ? dis[gR] : 0.f;
        }

#pragma unroll
    for (int nt = 0; nt < 4; ++nt) {
        f32x4 acc0 = {0.f, 0.f, 0.f, 0.f};
        f32x4 acc1 = {0.f, 0.f, 0.f, 0.f};
        int l = nt * 16 + m16;
#pragma unroll
        for (int kt = 0; kt < 4; ++kt) {
            frag_u Bh, Bl;
            Bh.q = sW[l * 17 + kt * 4 + quad];
            Bl.q = sW[1088 + l * 17 + kt * 4 + quad];
            acc0 = __builtin_amdgcn_mfma_f32_16x16x32_bf16(A[0][kt].v, Bl.v, acc0, 0, 0, 0);
            acc0 = __builtin_amdgcn_mfma_f32_16x16x32_bf16(A[0][kt].v, Bh.v, acc0, 0, 0, 0);
            acc1 = __builtin_amdgcn_mfma_f32_16x16x32_bf16(A[1][kt].v, Bl.v, acc1, 0, 0, 0);
            acc1 = __builtin_amdgcn_mfma_f32_16x16x32_bf16(A[1][kt].v, Bh.v, acc1, 0, 0, 0);
        }
#pragma unroll
        for (int r = 0; r < 4; ++r) {
            float vs0 = acc0[r] * dv[0][r];
            float vo0 = __shfl_xor(vs0, 1, 64);
            float vs1 = acc1[r] * dv[1][r];
            float vo1 = __shfl_xor(vs1, 1, 64);
            if ((m16 & 1) == 0) {
                int gR0 = mrow + quad * 4 + r;
                if (gR0 < M)
                    Hb[(size_t)gR0 * 32 + nt * 8 + (m16 >> 1)] = fp8pk(vs0, vo0);
                int gR1 = mrow + 16 + quad * 4 + r;
                if (gR1 < M)
                    Hb[(size_t)gR1 * 32 + nt * 8 + (m16 >> 1)] = fp8pk(vs1, vo1);
            }
        }
    }
}

// ====== Aggregate (fp8 input rows): lane owns 16 cols (16 B), zero shuffles ======
// LGS: log2 lanes/group (3 for L1's 128B row, 2 for L2's 64B row).
// SH:  log2 input row bytes (7 / 6). Output row (bf16) = 2^(SH-3) uint4.

template <int LGS, int SH>
__global__ __launch_bounds__(256) void k_aggf(
    const int* __restrict__ rowptr, const int* __restrict__ csr,
    const float* __restrict__ dis, const u16* __restrict__ Hb,
    const float* __restrict__ bias, u32* __restrict__ AGGb, int N)
{
    const int LG = 1 << LGS;
    const int OUT4 = 1 << (SH - 3);
    int gid = blockIdx.x * 256 + threadIdx.x;
    int n = gid >> LGS;
    int li = threadIdx.x & (LG - 1);
    if (n >= N) return;
    int e = rowptr[n];
    int s1 = rowptr[n + 1];
    const float dn = dis[n];
    const char* hb = (const char*)Hb;
    const u32 off = (u32)li << 4;

    f32x2 acc[8];
#pragma unroll
    for (int j = 0; j < 8; ++j) acc[j] = 0.f;

    for (; e + 8 <= s1; e += 8) {
        u32 a0 = (u32)csr[e + 0] << SH; u32 a1 = (u32)csr[e + 1] << SH;
        u32 a2 = (u32)csr[e + 2] << SH; u32 a3 = (u32)csr[e + 3] << SH;
        u32 a4 = (u32)csr[e + 4] << SH; u32 a5 = (u32)csr[e + 5] << SH;
        u32 a6 = (u32)csr[e + 6] << SH; u32 a7 = (u32)csr[e + 7] << SH;
        uint4 q0 = *(const uint4*)(hb + a0 + off);
        uint4 q1 = *(const uint4*)(hb + a1 + off);
        uint4 q2 = *(const uint4*)(hb + a2 + off);
        uint4 q3 = *(const uint4*)(hb + a3 + off);
        uint4 q4 = *(const uint4*)(hb + a4 + off);
        uint4 q5 = *(const uint4*)(hb + a5 + off);
        uint4 q6 = *(const uint4*)(hb + a6 + off);
        uint4 q7 = *(const uint4*)(hb + a7 + off);
        add16p(acc, q0); add16p(acc, q1); add16p(acc, q2); add16p(acc, q3);
        add16p(acc, q4); add16p(acc, q5); add16p(acc, q6); add16p(acc, q7);
    }
    for (; e + 2 <= s1; e += 2) {
        u32 a0 = (u32)csr[e + 0] << SH; u32 a1 = (u32)csr[e + 1] << SH;
        uint4 q0 = *(const uint4*)(hb + a0 + off);
        uint4 q1 = *(const uint4*)(hb + a1 + off);
        add16p(acc, q0); add16p(acc, q1);
    }
    if (e < s1) {
        u32 a0 = (u32)csr[e] << SH;
        uint4 q0 = *(const uint4*)(hb + a0 + off);
        add16p(acc, q0);
    }
    {   // self-loop: + own (already dis-scaled) row
        uint4 q = *(const uint4*)(hb + ((u32)n << SH) + off);
        add16p(acc, q);
    }

    // cols [li*16, li*16+16): o = dn*acc + bias, pack bf16 pairs
    const float4* bb = (const float4*)bias + li * 4;
    float4 b0_ = bb[0], b1_ = bb[1], b2_ = bb[2], b3_ = bb[3];
    uint4 p0, p1;
    p0.x = bf16_rne(fmaf(dn, acc[0].x, b0_.x)) | (bf16_rne(fmaf(dn, acc[0].y, b0_.y)) << 16);
    p0.y = bf16_rne(fmaf(dn, acc[1].x, b0_.z)) | (bf16_rne(fmaf(dn, acc[1].y, b0_.w)) << 16);
    p0.z = bf16_rne(fmaf(dn, acc[2].x, b1_.x)) | (bf16_rne(fmaf(dn, acc[2].y, b1_.y)) << 16);
    p0.w = bf16_rne(fmaf(dn, acc[3].x, b1_.z)) | (bf16_rne(fmaf(dn, acc[3].y, b1_.w)) << 16);
    p1.x = bf16_rne(fmaf(dn, acc[4].x, b2_.x)) | (bf16_rne(fmaf(dn, acc[4].y, b2_.y)) << 16);
    p1.y = bf16_rne(fmaf(dn, acc[5].x, b2_.z)) | (bf16_rne(fmaf(dn, acc[5].y, b2_.w)) << 16);
    p1.z = bf16_rne(fmaf(dn, acc[6].x, b3_.x)) | (bf16_rne(fmaf(dn, acc[6].y, b3_.y)) << 16);
    p1.w = bf16_rne(fmaf(dn, acc[7].x, b3_.z)) | (bf16_rne(fmaf(dn, acc[7].y, b3_.w)) << 16);
    ((uint4*)AGGb)[(size_t)n * OUT4 + li * 2 + 0] = p0;
    ((uint4*)AGGb)[(size_t)n * OUT4 + li * 2 + 1] = p1;
}

// ========= mean pool over sorted batch (bf16 input) + fused classifier =========

__device__ inline int lower_bound(const int* __restrict__ b, int n, int v) {
    int lo = 0, hi = n;
    while (lo < hi) { int m = (lo + hi) >> 1; if (b[m] < v) lo = m + 1; else hi = m; }
    return lo;
}

__global__ __launch_bounds__(256) void k_poolfc(
    const int* __restrict__ batch, const u32* __restrict__ AGGb2,
    const float* __restrict__ Wfc, const float* __restrict__ bfc,
    float* __restrict__ out, int n)
{
    int g = blockIdx.x;
    int start = lower_bound(batch, n, g);
    int end   = lower_bound(batch, n, g + 1);
    int tid = threadIdx.x;
    int f = tid & 63, stripe = tid >> 6;
    int ui = f >> 1, hi = f & 1;
    float acc = 0.f;
    for (int i = start + stripe; i < end; i += 4) {
        u32 v = AGGb2[(size_t)i * 32 + ui];
        acc += hi ? bf_hi(v) : bf_lo(v);
    }
    __shared__ float red[256];
    __shared__ float mean[64];
    red[tid] = acc;
    __syncthreads();
    if (tid < 64) {
        float s = red[tid] + red[tid + 64] + red[tid + 128] + red[tid + 192];
        float c = (float)(end - start);
        mean[tid] = s / fmaxf(c, 1.0f);
    }
    __syncthreads();
    if (tid < 10) {
        float o = bfc[tid];
        for (int k = 0; k < 64; ++k)
            o = fmaf(mean[k], Wfc[k * 10 + tid], o);
        out[g * 10 + tid] = o;
    }
}

// ================= launch =================

extern "C" void kernel_launch(void* const* d_in, const int* in_sizes, int n_in,
                              void* d_out, int out_size, void* d_ws, size_t ws_size,
                              hipStream_t stream)
{
    const float* x    = (const float*)d_in[0];
    const int*   ei   = (const int*)d_in[1];
    const int*   batch= (const int*)d_in[2];
    const float* W1   = (const float*)d_in[3];
    const float* b1   = (const float*)d_in[4];
    const float* W2   = (const float*)d_in[5];
    const float* b2   = (const float*)d_in[6];
    const float* Wfc  = (const float*)d_in[7];
    const float* bfc  = (const float*)d_in[8];
    float* out = (float*)d_out;

    const int N  = in_sizes[0] / 128;     // 100000
    const int E  = in_sizes[1] / 2;       // 3200000
    const int ng = out_size / 10;         // 256

    const int NBK = (N + BKW - 1) / BKW;  // 391 buckets

    // ---- workspace layout (words) ----
    int*   rowptr    = (int*)d_ws;                          // 102400 (N+1)
    int*   bucketCur = rowptr + 102400;                     // 512
    float* dis       = (float*)(bucketCur + 512);           // 102400
    int*   csr       = (int*)(dis + 102400);                // E
    // region A: tmp (NBK*CAP=3.60M words) aliases Hb1 (N*32 words, fp8) and agg2b
    u32*   tmp       = (u32*)(csr + E);
    u16*   Hb1       = (u16*)tmp;                               // N*64 u16 (fp8, 128B/row)
    u32*   agg2b     = tmp;                                     // N*32 u32 (aliases Hb1; Hb1 dead
                                                                // before agg2 runs — gemm2 reads
                                                                // agg1b, agg2 reads Hb2)
    u32*   agg1b     = (u32*)((int*)tmp + (size_t)N * 64);      // N*64 u32 (bf16 packed)
    u16*   Hb2       = (u16*)((int*)agg1b + (size_t)N * 128);   // N*32 u16 (fp8, 64B/row)
    u32*   W1h       = (u32*)((int*)Hb2 + (size_t)N * 32);      // 8192
    u32*   W1l       = W1h + 8192;                              // 8192
    u32*   W2h       = W1l + 8192;                              // 4096
    u32*   W2l       = W2h + 4096;                              // 4096

    // ---- weight convert (+ bucketCur zero) + CSR build ----
    k_convW<<<48, 256, 0, stream>>>(W1, W2, W1h, W1l, W2h, W2l, bucketCur, NBK);
    k_part1<<<(E + TILE1 - 1) / TILE1, 512, 0, stream>>>(ei, bucketCur, tmp, E, N, NBK);
    k_part2<<<NBK, 512, 0, stream>>>(bucketCur, tmp, csr, rowptr, dis, N, NBK);

    // ---- layer 1 ----
    k_gemm1m<<<(N + 127) / 128, 256, 0, stream>>>(x, W1h, W1l, dis, Hb1, N);
    k_aggf<3, 7><<<(N * 8 + 255) / 256, 256, 0, stream>>>(rowptr, csr, dis, Hb1, b1, agg1b, N);

    // ---- layer 2 ----
    k_gemm2m<<<(N + 127) / 128, 256, 0, stream>>>(agg1b, W2h, W2l, dis, Hb2, N);
    k_aggf<2, 6><<<(N * 4 + 255) / 256, 256, 0, stream>>>(rowptr, csr, dis, Hb2, b2, agg2b, N);

    // ---- pool + classifier (fused) ----
    k_poolfc<<<ng, 256, 0, stream>>>(batch, agg2b, Wfc, bfc, out, N);
}

// Round 13
// 335.528 us; speedup vs baseline: 2.0936x; 1.0082x over previous
//
#include <hip/hip_runtime.h>
#include <math.h>

typedef unsigned int  u32;
typedef unsigned short u16;

#define TILE1 8192      // edges per pass-1 block (16/thread @ 512 threads)
#define BKW   256       // nodes per bucket (shift 8)
#define CAP   9216      // tmp slots per bucket (mean 8192, +11 sigma)

typedef __attribute__((ext_vector_type(8))) short bf16x8;
typedef __attribute__((ext_vector_type(4))) float f32x4;
typedef __attribute__((ext_vector_type(2))) float f32x2;
union frag_u { bf16x8 v; u32 u[4]; uint4 q; };

__device__ inline u32 bf16_rne(float f) {
    u32 u = __float_as_uint(f);
    return (u + 0x7FFFu + ((u >> 16) & 1u)) >> 16;
}
__device__ inline float bf_lo(u32 u) { return __uint_as_float(u << 16); }
__device__ inline float bf_hi(u32 u) { return __uint_as_float(u & 0xFFFF0000u); }

__device__ inline f32x2 up2(u32 u) {
    f32x2 t;
    t.x = __uint_as_float(u << 16);
    t.y = __uint_as_float(u & 0xFFFF0000u);
    return t;
}

// ---- fp8 e4m3 (OCP on gfx950) pack/unpack via HW converts ----
// word selector must be a LITERAL (R11 lesson) -> two wrappers.
__device__ inline u16 fp8pk(float a, float b) {
    return (u16)(__builtin_amdgcn_cvt_pk_fp8_f32(a, b, 0, false) & 0xFFFF);
}
__device__ inline f32x2 pk8lo(u32 w) {
    f32x2 r = __builtin_amdgcn_cvt_pk_f32_fp8(w, false);
    return r;
}
__device__ inline f32x2 pk8hi(u32 w) {
    f32x2 r = __builtin_amdgcn_cvt_pk_f32_fp8(w, true);
    return r;
}
// 16 fp8 -> 16 f32 accumulate (8 cvt + 8 pk-adds)
__device__ inline void add16p(f32x2* a, uint4 q) {
    a[0] += pk8lo(q.x); a[1] += pk8hi(q.x);
    a[2] += pk8lo(q.y); a[3] += pk8hi(q.y);
    a[4] += pk8lo(q.z); a[5] += pk8hi(q.z);
    a[6] += pk8lo(q.w); a[7] += pk8hi(q.w);
}

// relu on packed bf16x2: clear halves whose sign bit is set
__device__ inline u32 relu_pk(u32 v) {
    u32 s = v & 0x80008000u;
    u32 m = (s >> 15) * 0xFFFFu;
    return v & ~m;
}

// ================= CSR build: 2-pass radix partition =================

__global__ __launch_bounds__(512) void k_part1(const int* __restrict__ ei,
                                               int* __restrict__ bucketCur,
                                               u32* __restrict__ tmp,
                                               int E, int N, int NBK) {
    __shared__ int hist[2048];    // 4 replicas for count; [0:512) reused as cursor
    __shared__ int base[512];
    const int tid = threadIdx.x;
    if (tid < NBK) {
        hist[tid] = 0; hist[512 + tid] = 0;
        hist[1024 + tid] = 0; hist[1536 + tid] = 0;
    }
    __syncthreads();

    const int rep = (tid & 3) << 9;
    const int t0 = blockIdx.x * TILE1;
    const int4* ei4s = (const int4*)ei;             // E % 4 == 0
    const int4* ei4d = (const int4*)(ei + E);
    const int q0 = t0 >> 2;
    const int QE = E >> 2;

    int sv[16], dv[16], key[16];
#pragma unroll
    for (int j = 0; j < 4; ++j) {
        int qi = q0 + j * 512 + tid;
        int4 s4 = make_int4(0, 0, 0, 0), d4 = make_int4(-1, -1, -1, -1);
        if (qi < QE) { s4 = ei4s[qi]; d4 = ei4d[qi]; }
        sv[4 * j + 0] = s4.x; dv[4 * j + 0] = d4.x;
        sv[4 * j + 1] = s4.y; dv[4 * j + 1] = d4.y;
        sv[4 * j + 2] = s4.z; dv[4 * j + 2] = d4.z;
        sv[4 * j + 3] = s4.w; dv[4 * j + 3] = d4.w;
    }
#pragma unroll
    for (int j = 0; j < 16; ++j) {
        key[j] = -1;
        if ((unsigned)dv[j] < (unsigned)N && (unsigned)sv[j] < (unsigned)N) {
            key[j] = dv[j] >> 8;
            atomicAdd(&hist[key[j] + rep], 1);
        }
    }
    __syncthreads();
    if (tid < NBK) {
        int tot = hist[tid] + hist[512 + tid] + hist[1024 + tid] + hist[1536 + tid];
        base[tid] = atomicAdd(&bucketCur[tid], tot);
        hist[tid] = 0;                 // running cursor for placement
    }
    __syncthreads();
#pragma unroll
    for (int j = 0; j < 16; ++j) {
        if (key[j] >= 0) {
            int slot = atomicAdd(&hist[key[j]], 1);
            int off = base[key[j]] + slot;
            if (off < CAP)
                tmp[(size_t)key[j] * CAP + off] =
                    ((u32)(dv[j] & 255) << 17) | (u32)sv[j];
        }
    }
}

__global__ __launch_bounds__(512) void k_part2(const int* __restrict__ bucketCnt,
                                               const u32* __restrict__ tmp,
                                               int* __restrict__ csr,
                                               int* __restrict__ rowptr,
                                               float* __restrict__ dis,
                                               int N, int NBK) {
    __shared__ int hist[256];
    __shared__ int ts[512];
    __shared__ int sStart;
    const int b = blockIdx.x;
    const int t = threadIdx.x;

    int myCnt = (t < NBK) ? bucketCnt[t] : 0;
    ts[t] = myCnt;
    __syncthreads();
    for (int off = 1; off < 512; off <<= 1) {
        int u = (t >= off) ? ts[t - off] : 0;
        __syncthreads();
        ts[t] += u;
        __syncthreads();
    }
    if (t == b) sStart = ts[t] - myCnt;
    if (b == 0 && t == NBK - 1) rowptr[N] = ts[t];
    __syncthreads();
    const int start = sStart;
    const int cnt = bucketCnt[b];
    const u32* src = tmp + (size_t)b * CAP;

    if (t < 256) hist[t] = 0;
    __syncthreads();
    for (int i = t; i < cnt; i += 512)
        atomicAdd(&hist[src[i] >> 17], 1);
    __syncthreads();

    int h = (t < 256) ? hist[t] : 0;
    ts[t] = h;
    __syncthreads();
    for (int off = 1; off < 512; off <<= 1) {
        int u = (t >= off) ? ts[t - off] : 0;
        __syncthreads();
        ts[t] += u;
        __syncthreads();
    }
    if (t < 256) hist[t] = ts[t] - h;       // exclusive
    __syncthreads();

    if (t < 256) {
        int gn = (b << 8) + t;
        if (gn < N) {
            int e0 = hist[t];
            int e1 = (t < 255) ? hist[t + 1] : cnt;
            rowptr[gn] = start + e0;
            dis[gn] = rsqrtf((float)(e1 - e0) + 1.0f);
        }
    }
    __syncthreads();

    for (int i = t; i < cnt; i += 512) {
        u32 v = src[i];
        int p = atomicAdd(&hist[v >> 17], 1);
        csr[start + p] = (int)(v & 0x1FFFFu);
    }
}

// ========== weight convert (+ bucketCur zero): n-major bf16 hi/lo tables ==========

__global__ __launch_bounds__(256) void k_convW(
    const float* __restrict__ W1, const float* __restrict__ W2,
    u32* __restrict__ W1h, u32* __restrict__ W1l,
    u32* __restrict__ W2h, u32* __restrict__ W2l,
    int* __restrict__ bucketCur, int NBK)
{
    int idx = blockIdx.x * 256 + threadIdx.x;
    if (idx < NBK) bucketCur[idx] = 0;
    if (idx < 8192) {
        int n = idx >> 6, k = (idx & 63) * 2;
        float w0 = W1[k * 128 + n], w1 = W1[(k + 1) * 128 + n];
        u32 h0 = bf16_rne(w0), h1 = bf16_rne(w1);
        u32 l0 = bf16_rne(w0 - __uint_as_float(h0 << 16));
        u32 l1 = bf16_rne(w1 - __uint_as_float(h1 << 16));
        W1h[idx] = h0 | (h1 << 16);
        W1l[idx] = l0 | (l1 << 16);
    } else if (idx < 12288) {
        int i2 = idx - 8192;
        int n = i2 >> 6, k = (i2 & 63) * 2;
        float w0 = W2[k * 64 + n], w1 = W2[(k + 1) * 64 + n];
        u32 h0 = bf16_rne(w0), h1 = bf16_rne(w1);
        u32 l0 = bf16_rne(w0 - __uint_as_float(h0 << 16));
        u32 l1 = bf16_rne(w1 - __uint_as_float(h1 << 16));
        W2h[i2] = h0 | (h1 << 16);
        W2l[i2] = l0 | (l1 << 16);
    }
}

// ========== GEMM1 (MFMA, LDS-staged W): Hb1 = fp8( (X @ W1) * dis ) ==========
// 2 M-tiles per wave (32 rows). Block covers 128 rows; 64 KB LDS, XOR-swizzled.
// Output row = 128 fp8 = 128 B.

__global__ __launch_bounds__(256) void k_gemm1m(
    const float* __restrict__ X, const u32* __restrict__ Wh,
    const u32* __restrict__ Wl, const float* __restrict__ dis,
    u16* __restrict__ Hb, int M)
{
    __shared__ uint4 sW[4096];
    const int tid = threadIdx.x;
    const uint4* Wh4 = (const uint4*)Wh;
    const uint4* Wl4 = (const uint4*)Wl;
#pragma unroll
    for (int i = 0; i < 8; ++i) {
        int idx = tid + i * 256;          // 0..2047
        int l = idx >> 4, j = idx & 15;
        int js = j ^ (l & 7);
        sW[l * 16 + js] = Wh4[idx];
        sW[2048 + l * 16 + js] = Wl4[idx];
    }
    __syncthreads();

    const int w = tid >> 6, lane = tid & 63;
    const int mrow = blockIdx.x * 128 + w * 32;
    const int m16 = lane & 15, quad = lane >> 4;

    frag_u Ah[2][4], Al[2][4];
#pragma unroll
    for (int t = 0; t < 2; ++t) {
        int gm = mrow + t * 16 + m16; if (gm >= M) gm = M - 1;
        const float* xr = X + (size_t)gm * 128;
#pragma unroll
        for (int kt = 0; kt < 4; ++kt) {
            int kb = kt * 32 + quad * 8;
            float4 xa = *(const float4*)(xr + kb);
            float4 xb = *(const float4*)(xr + kb + 4);
            float xe[8] = {xa.x, xa.y, xa.z, xa.w, xb.x, xb.y, xb.z, xb.w};
#pragma unroll
            for (int j = 0; j < 4; ++j) {
                u32 h0 = bf16_rne(xe[2 * j]),     h1 = bf16_rne(xe[2 * j + 1]);
                u32 l0 = bf16_rne(xe[2 * j]     - __uint_as_float(h0 << 16));
                u32 l1 = bf16_rne(xe[2 * j + 1] - __uint_as_float(h1 << 16));
                Ah[t][kt].u[j] = h0 | (h1 << 16);
                Al[t][kt].u[j] = l0 | (l1 << 16);
            }
        }
    }

    float dv[2][4];
#pragma unroll
    for (int t = 0; t < 2; ++t)
#pragma unroll
        for (int r = 0; r < 4; ++r) {
            int gR = mrow + t * 16 + quad * 4 + r;
            dv[t][r] = (gR < M) ? dis[gR] : 0.f;
        }

#pragma unroll
    for (int nt = 0; nt < 8; ++nt) {
        f32x4 acc0 = {0.f, 0.f, 0.f, 0.f};
        f32x4 acc1 = {0.f, 0.f, 0.f, 0.f};
        int l = nt * 16 + m16;
        int swz = l & 7;
#pragma unroll
        for (int kt = 0; kt < 4; ++kt) {
            frag_u Bh, Bl;
            int jb = (kt * 4 + quad) ^ swz;
            Bh.q = sW[l * 16 + jb];
            Bl.q = sW[2048 + l * 16 + jb];
            acc0 = __builtin_amdgcn_mfma_f32_16x16x32_bf16(Al[0][kt].v, Bh.v, acc0, 0, 0, 0);
            acc0 = __builtin_amdgcn_mfma_f32_16x16x32_bf16(Ah[0][kt].v, Bl.v, acc0, 0, 0, 0);
            acc0 = __builtin_amdgcn_mfma_f32_16x16x32_bf16(Ah[0][kt].v, Bh.v, acc0, 0, 0, 0);
            acc1 = __builtin_amdgcn_mfma_f32_16x16x32_bf16(Al[1][kt].v, Bh.v, acc1, 0, 0, 0);
            acc1 = __builtin_amdgcn_mfma_f32_16x16x32_bf16(Ah[1][kt].v, Bl.v, acc1, 0, 0, 0);
            acc1 = __builtin_amdgcn_mfma_f32_16x16x32_bf16(Ah[1][kt].v, Bh.v, acc1, 0, 0, 0);
        }
#pragma unroll
        for (int r = 0; r < 4; ++r) {
            float vs0 = acc0[r] * dv[0][r];
            float vo0 = __shfl_xor(vs0, 1, 64);
            float vs1 = acc1[r] * dv[1][r];
            float vo1 = __shfl_xor(vs1, 1, 64);
            if ((m16 & 1) == 0) {
                int gR0 = mrow + quad * 4 + r;
                if (gR0 < M)
                    Hb[(size_t)gR0 * 64 + nt * 8 + (m16 >> 1)] = fp8pk(vs0, vo0);
                int gR1 = mrow + 16 + quad * 4 + r;
                if (gR1 < M)
                    Hb[(size_t)gR1 * 64 + nt * 8 + (m16 >> 1)] = fp8pk(vs1, vo1);
            }
        }
    }
}

// ========== GEMM2 (MFMA, LDS-staged W): Hb2 = fp8( (relu(agg1b) @ W2) * dis ) ==========
// 2 M-tiles per wave, block covers 128 rows. Output row = 64 fp8 = 64 B.

__global__ __launch_bounds__(256) void k_gemm2m(
    const u32* __restrict__ Xb, const u32* __restrict__ Wh,
    const u32* __restrict__ Wl, const float* __restrict__ dis,
    u16* __restrict__ Hb, int M)
{
    __shared__ uint4 sW[2176];
    const int tid = threadIdx.x;
    const uint4* Wh4 = (const uint4*)Wh;
    const uint4* Wl4 = (const uint4*)Wl;
#pragma unroll
    for (int i = 0; i < 4; ++i) {
        int idx = tid + i * 256;
        int l = idx >> 4, j = idx & 15;
        sW[l * 17 + j] = Wh4[l * 16 + j];
        sW[1088 + l * 17 + j] = Wl4[l * 16 + j];
    }
    __syncthreads();

    const int w = tid >> 6, lane = tid & 63;
    const int mrow = blockIdx.x * 128 + w * 32;
    const int m16 = lane & 15, quad = lane >> 4;

    const uint4* X4 = (const uint4*)Xb;
    frag_u A[2][4];
#pragma unroll
    for (int t = 0; t < 2; ++t) {
        int gm = mrow + t * 16 + m16; if (gm >= M) gm = M - 1;
#pragma unroll
        for (int kt = 0; kt < 4; ++kt) {
            A[t][kt].q = X4[(size_t)gm * 16 + kt * 4 + quad];
#pragma unroll
            for (int j = 0; j < 4; ++j) A[t][kt].u[j] = relu_pk(A[t][kt].u[j]);
        }
    }

    float dv[2][4];
#pragma unroll
    for (int t = 0; t < 2; ++t)
#pragma unroll
        for (int r = 0; r < 4; ++r) {
            int gR = mrow + t * 16 + quad * 4 + r;
            dv[t][r] = (gR < M) ? dis[gR] : 0.f;
        }

#pragma unroll
    for (int nt = 0; nt < 4; ++nt) {
        f32x4 acc0 = {0.f, 0.f, 0.f, 0.f};
        f32x4 acc1 = {0.f, 0.f, 0.f, 0.f};
        int l = nt * 16 + m16;
#pragma unroll
        for (int kt = 0; kt < 4; ++kt) {
            frag_u Bh, Bl;
            Bh.q = sW[l * 17 + kt * 4 + quad];
            Bl.q = sW[1088 + l * 17 + kt * 4 + quad];
            acc0 = __builtin_amdgcn_mfma_f32_16x16x32_bf16(A[0][kt].v, Bl.v, acc0, 0, 0, 0);
            acc0 = __builtin_amdgcn_mfma_f32_16x16x32_bf16(A[0][kt].v, Bh.v, acc0, 0, 0, 0);
            acc1 = __builtin_amdgcn_mfma_f32_16x16x32_bf16(A[1][kt].v, Bl.v, acc1, 0, 0, 0);
            acc1 = __builtin_amdgcn_mfma_f32_16x16x32_bf16(A[1][kt].v, Bh.v, acc1, 0, 0, 0);
        }
#pragma unroll
        for (int r = 0; r < 4; ++r) {
            float vs0 = acc0[r] * dv[0][r];
            float vo0 = __shfl_xor(vs0, 1, 64);
            float vs1 = acc1[r] * dv[1][r];
            float vo1 = __shfl_xor(vs1, 1, 64);
            if ((m16 & 1) == 0) {
                int gR0 = mrow + quad * 4 + r;
                if (gR0 < M)
                    Hb[(size_t)gR0 * 32 + nt * 8 + (m16 >> 1)] = fp8pk(vs0, vo0);
                int gR1 = mrow + 16 + quad * 4 + r;
                if (gR1 < M)
                    Hb[(size_t)gR1 * 32 + nt * 8 + (m16 >> 1)] = fp8pk(vs1, vo1);
            }
        }
    }
}

// ====== Aggregate (fp8 rows): TWO sub-groups per node (edge-range split) ======
// R12 halved wave count vs R10 (occupancy 58->34%) and lost gather TLP; this
// restores it: 2*LG lanes per node, sub-group s handles [e0,mid)/[mid,s1),
// combine via one shfl_xor(LG) per acc pair (sub-pairs are wave-internal:
// 2*LG <= 16). Self-loop in sub 1 (covers deg-0). Only sub 0 stores.
// LGS: log2 lanes per sub-group (3 for L1 128B row, 2 for L2 64B row).

template <int LGS, int SH>
__global__ __launch_bounds__(256) void k_aggf(
    const int* __restrict__ rowptr, const int* __restrict__ csr,
    const float* __restrict__ dis, const u16* __restrict__ Hb,
    const float* __restrict__ bias, u32* __restrict__ AGGb, int N)
{
    const int LG = 1 << LGS;
    const int OUT4 = 1 << (SH - 3);
    int gid = blockIdx.x * 256 + threadIdx.x;
    int n = gid >> (LGS + 1);
    int sub = (threadIdx.x >> LGS) & 1;
    int li = threadIdx.x & (LG - 1);
    if (n >= N) return;
    int e0 = rowptr[n];
    int s1 = rowptr[n + 1];
    int mid = (e0 + s1) >> 1;
    int e  = sub ? mid : e0;
    int en = sub ? s1  : mid;
    const float dn = dis[n];
    const char* hb = (const char*)Hb;
    const u32 off = (u32)li << 4;

    f32x2 acc[8];
#pragma unroll
    for (int j = 0; j < 8; ++j) acc[j] = 0.f;

    for (; e + 8 <= en; e += 8) {
        u32 a0 = (u32)csr[e + 0] << SH; u32 a1 = (u32)csr[e + 1] << SH;
        u32 a2 = (u32)csr[e + 2] << SH; u32 a3 = (u32)csr[e + 3] << SH;
        u32 a4 = (u32)csr[e + 4] << SH; u32 a5 = (u32)csr[e + 5] << SH;
        u32 a6 = (u32)csr[e + 6] << SH; u32 a7 = (u32)csr[e + 7] << SH;
        uint4 q0 = *(const uint4*)(hb + a0 + off);
        uint4 q1 = *(const uint4*)(hb + a1 + off);
        uint4 q2 = *(const uint4*)(hb + a2 + off);
        uint4 q3 = *(const uint4*)(hb + a3 + off);
        uint4 q4 = *(const uint4*)(hb + a4 + off);
        uint4 q5 = *(const uint4*)(hb + a5 + off);
        uint4 q6 = *(const uint4*)(hb + a6 + off);
        uint4 q7 = *(const uint4*)(hb + a7 + off);
        add16p(acc, q0); add16p(acc, q1); add16p(acc, q2); add16p(acc, q3);
        add16p(acc, q4); add16p(acc, q5); add16p(acc, q6); add16p(acc, q7);
    }
    for (; e + 2 <= en; e += 2) {
        u32 a0 = (u32)csr[e + 0] << SH; u32 a1 = (u32)csr[e + 1] << SH;
        uint4 q0 = *(const uint4*)(hb + a0 + off);
        uint4 q1 = *(const uint4*)(hb + a1 + off);
        add16p(acc, q0); add16p(acc, q1);
    }
    if (e < en) {
        u32 a0 = (u32)csr[e] << SH;
        uint4 q0 = *(const uint4*)(hb + a0 + off);
        add16p(acc, q0);
    }
    if (sub) {   // self-loop: + own (already dis-scaled) row — exactly once
        uint4 q = *(const uint4*)(hb + ((u32)n << SH) + off);
        add16p(acc, q);
    }

    // combine the two sub-groups (partner lane = lane ^ LG, same li)
#pragma unroll
    for (int j = 0; j < 8; ++j) {
        acc[j].x += __shfl_xor(acc[j].x, LG, 64);
        acc[j].y += __shfl_xor(acc[j].y, LG, 64);
    }

    if (sub == 0) {
        // cols [li*16, li*16+16): o = dn*acc + bias, pack bf16 pairs
        const float4* bb = (const float4*)bias + li * 4;
        float4 b0_ = bb[0], b1_ = bb[1], b2_ = bb[2], b3_ = bb[3];
        uint4 p0, p1;
        p0.x = bf16_rne(fmaf(dn, acc[0].x, b0_.x)) | (bf16_rne(fmaf(dn, acc[0].y, b0_.y)) << 16);
        p0.y = bf16_rne(fmaf(dn, acc[1].x, b0_.z)) | (bf16_rne(fmaf(dn, acc[1].y, b0_.w)) << 16);
        p0.z = bf16_rne(fmaf(dn, acc[2].x, b1_.x)) | (bf16_rne(fmaf(dn, acc[2].y, b1_.y)) << 16);
        p0.w = bf16_rne(fmaf(dn, acc[3].x, b1_.z)) | (bf16_rne(fmaf(dn, acc[3].y, b1_.w)) << 16);
        p1.x = bf16_rne(fmaf(dn, acc[4].x, b2_.x)) | (bf16_rne(fmaf(dn, acc[4].y, b2_.y)) << 16);
        p1.y = bf16_rne(fmaf(dn, acc[5].x, b2_.z)) | (bf16_rne(fmaf(dn, acc[5].y, b2_.w)) << 16);
        p1.z = bf16_rne(fmaf(dn, acc[6].x, b3_.x)) | (bf16_rne(fmaf(dn, acc[6].y, b3_.y)) << 16);
        p1.w = bf16_rne(fmaf(dn, acc[7].x, b3_.z)) | (bf16_rne(fmaf(dn, acc[7].y, b3_.w)) << 16);
        ((uint4*)AGGb)[(size_t)n * OUT4 + li * 2 + 0] = p0;
        ((uint4*)AGGb)[(size_t)n * OUT4 + li * 2 + 1] = p1;
    }
}

// ========= mean pool over sorted batch (bf16 input) + fused classifier =========

__device__ inline int lower_bound(const int* __restrict__ b, int n, int v) {
    int lo = 0, hi = n;
    while (lo < hi) { int m = (lo + hi) >> 1; if (b[m] < v) lo = m + 1; else hi = m; }
    return lo;
}

__global__ __launch_bounds__(256) void k_poolfc(
    const int* __restrict__ batch, const u32* __restrict__ AGGb2,
    const float* __restrict__ Wfc, const float* __restrict__ bfc,
    float* __restrict__ out, int n)
{
    int g = blockIdx.x;
    int start = lower_bound(batch, n, g);
    int end   = lower_bound(batch, n, g + 1);
    int tid = threadIdx.x;
    int f = tid & 63, stripe = tid >> 6;
    int ui = f >> 1, hi = f & 1;
    float acc = 0.f;
    for (int i = start + stripe; i < end; i += 4) {
        u32 v = AGGb2[(size_t)i * 32 + ui];
        acc += hi ? bf_hi(v) : bf_lo(v);
    }
    __shared__ float red[256];
    __shared__ float mean[64];
    red[tid] = acc;
    __syncthreads();
    if (tid < 64) {
        float s = red[tid] + red[tid + 64] + red[tid + 128] + red[tid + 192];
        float c = (float)(end - start);
        mean[tid] = s / fmaxf(c, 1.0f);
    }
    __syncthreads();
    if (tid < 10) {
        float o = bfc[tid];
        for (int k = 0; k < 64; ++k)
            o = fmaf(mean[k], Wfc[k * 10 + tid], o);
        out[g * 10 + tid] = o;
    }
}

// ================= launch =================

extern "C" void kernel_launch(void* const* d_in, const int* in_sizes, int n_in,
                              void* d_out, int out_size, void* d_ws, size_t ws_size,
                              hipStream_t stream)
{
    const float* x    = (const float*)d_in[0];
    const int*   ei   = (const int*)d_in[1];
    const int*   batch= (const int*)d_in[2];
    const float* W1   = (const float*)d_in[3];
    const float* b1   = (const float*)d_in[4];
    const float* W2   = (const float*)d_in[5];
    const float* b2   = (const float*)d_in[6];
    const float* Wfc  = (const float*)d_in[7];
    const float* bfc  = (const float*)d_in[8];
    float* out = (float*)d_out;

    const int N  = in_sizes[0] / 128;     // 100000
    const int E  = in_sizes[1] / 2;       // 3200000
    const int ng = out_size / 10;         // 256

    const int NBK = (N + BKW - 1) / BKW;  // 391 buckets

    // ---- workspace layout (words) ----
    int*   rowptr    = (int*)d_ws;                          // 102400 (N+1)
    int*   bucketCur = rowptr + 102400;                     // 512
    float* dis       = (float*)(bucketCur + 512);           // 102400
    int*   csr       = (int*)(dis + 102400);                // E
    // region A: tmp (NBK*CAP=3.60M words) aliases Hb1 (N*32 words, fp8) and agg2b
    u32*   tmp       = (u32*)(csr + E);
    u16*   Hb1       = (u16*)tmp;                               // N*64 u16 (fp8, 128B/row)
    u32*   agg2b     = tmp;                                     // N*32 u32 (aliases Hb1; Hb1 dead
                                                                // before agg2 runs)
    u32*   agg1b     = (u32*)((int*)tmp + (size_t)N * 64);      // N*64 u32 (bf16 packed)
    u16*   Hb2       = (u16*)((int*)agg1b + (size_t)N * 128);   // N*32 u16 (fp8, 64B/row)
    u32*   W1h       = (u32*)((int*)Hb2 + (size_t)N * 32);      // 8192
    u32*   W1l       = W1h + 8192;                              // 8192
    u32*   W2h       = W1l + 8192;                              // 4096
    u32*   W2l       = W2h + 4096;                              // 4096

    // ---- weight convert (+ bucketCur zero) + CSR build ----
    k_convW<<<48, 256, 0, stream>>>(W1, W2, W1h, W1l, W2h, W2l, bucketCur, NBK);
    k_part1<<<(E + TILE1 - 1) / TILE1, 512, 0, stream>>>(ei, bucketCur, tmp, E, N, NBK);
    k_part2<<<NBK, 512, 0, stream>>>(bucketCur, tmp, csr, rowptr, dis, N, NBK);

    // ---- layer 1 ----
    k_gemm1m<<<(N + 127) / 128, 256, 0, stream>>>(x, W1h, W1l, dis, Hb1, N);
    k_aggf<3, 7><<<(N * 16 + 255) / 256, 256, 0, stream>>>(rowptr, csr, dis, Hb1, b1, agg1b, N);

    // ---- layer 2 ----
    k_gemm2m<<<(N + 127) / 128, 256, 0, stream>>>(agg1b, W2h, W2l, dis, Hb2, N);
    k_aggf<2, 6><<<(N * 8 + 255) / 256, 256, 0, stream>>>(rowptr, csr, dis, Hb2, b2, agg2b, N);

    // ---- pool + classifier (fused) ----
    k_poolfc<<<ng, 256, 0, stream>>>(batch, agg2b, Wfc, bfc, out, N);
}